// Round 6
// baseline (734.553 us; speedup 1.0000x reference)
//
#include <hip/hip_runtime.h>
#include <cstdint>
#include <cstddef>

#define INORM_EPS 1e-5f

typedef _Float16 f16;
typedef f16 f16x8 __attribute__((ext_vector_type(8)));
typedef f16 f16x4 __attribute__((ext_vector_type(4)));
typedef f16 f16x2 __attribute__((ext_vector_type(2)));
typedef float f32x4 __attribute__((ext_vector_type(4)));

// Channel slot layout: mem slot m in [0,32) holds real channel (m>>1)+(m&1)*16.
// Lane's two MFMA accs (co n, co n+16) land in slots 2n, 2n+1 -> f16x2 stores.

// ---------------- one merged prep kernel ----------------------------------
__global__ __launch_bounds__(256) void prep(
    const float* __restrict__ rbs_w1, const float* __restrict__ rbs_w2,
    const float* __restrict__ rb_w1, const float* __restrict__ rb_w2,
    const float* __restrict__ rbs_ws, const float* __restrict__ conv1_w,
    float2* __restrict__ SP, f16* __restrict__ wp3, f16* __restrict__ wp1,
    f16* __restrict__ wp7) {
  int i = blockIdx.x * 256 + threadIdx.x;
  if (i < 20480) { SP[i] = make_float2(0.f, 0.f); return; }
  i -= 20480;
  if (i < 92160) {  // 3x3 B-frags; ci slot-permuted
    int mat = i / 9216, r = i % 9216;
    int p = r >> 10, f = (r >> 9) & 1, l = (r >> 3) & 63, j = r & 7;
    int co = f * 16 + (l & 15);
    int kk = (l >> 4) * 8 + j;
    int ci = (kk >> 1) + ((kk & 1) << 4);  // slot -> real channel
    const float* src; int m;
    if (mat < 3) { src = rbs_w1; m = mat; }
    else if (mat < 6) { src = rbs_w2; m = mat - 3; }
    else if (mat < 8) { src = rb_w1; m = mat - 6; }
    else { src = rb_w2; m = mat - 8; }
    wp3[i] = (f16)src[m * 9216 + co * 288 + ci * 9 + p];
    return;
  }
  i -= 92160;
  if (i < 3072) {  // 1x1 B-frags; ci slot-permuted
    int mat = i / 1024, r = i % 1024;
    int f = r >> 9, l = (r >> 3) & 63, j = r & 7;
    int kk = (l >> 4) * 8 + j;
    int ci = (kk >> 1) + ((kk & 1) << 4);
    wp1[i] = (f16)rbs_ws[mat * 1024 + (f * 16 + (l & 15)) * 32 + ci];
    return;
  }
  i -= 3072;  // conv1 7x7 (input not permuted)
  int ky = i >> 10, f = (i >> 9) & 1, l = (i >> 3) & 63, j = i & 7;
  int k = (l >> 4) * 8 + j, kx = k >> 2, ci = k & 3;
  float v = 0.f;
  if (kx < 7 && ci < 3) v = conv1_w[(f * 16 + (l & 15)) * 147 + ci * 49 + ky * 7 + kx];
  wp7[i] = (f16)v;
}

// ---------------- raw (sum, sumsq) stats for fp32 input x -----------------
__global__ __launch_bounds__(256) void stats_raw(const float* __restrict__ in,
                                                 float2* __restrict__ st, int HW) {
  const float4* p = (const float4*)(in + (size_t)blockIdx.x * HW);
  float s = 0.f, ss = 0.f;
  int n4 = HW >> 2;
  for (int i = threadIdx.x; i < n4; i += 256) {
    float4 v = p[i];
    s += v.x + v.y + v.z + v.w;
    ss += v.x * v.x + v.y * v.y + v.z * v.z + v.w * v.w;
  }
  __shared__ float r0[256], r1[256];
  r0[threadIdx.x] = s;
  r1[threadIdx.x] = ss;
  __syncthreads();
  for (int off = 128; off > 0; off >>= 1) {
    if ((int)threadIdx.x < off) {
      r0[threadIdx.x] += r0[threadIdx.x + off];
      r1[threadIdx.x] += r1[threadIdx.x + off];
    }
    __syncthreads();
  }
  if (threadIdx.x == 0) st[blockIdx.x] = make_float2(r0[0], r1[0]);
}

// ---- pack x: fp32 NCHW -> normed padded f16 [64][262][262][4] ------------
__global__ __launch_bounds__(256) void packx(const float* __restrict__ x,
                                             const float2* __restrict__ SPx,
                                             f16* __restrict__ xP) {
  int u = blockIdx.x * 256 + threadIdx.x;
  if (u >= 262 * 262) return;
  int b = blockIdx.z;
  int r = u / 262, c = u % 262;
  f16x4 out;
  out[0] = (f16)0; out[1] = (f16)0; out[2] = (f16)0; out[3] = (f16)0;
  if (r >= 3 && r < 259 && c >= 3 && c < 259) {
    int ir = r - 3, ic = c - 3;
#pragma unroll
    for (int ci = 0; ci < 3; ci++) {
      float2 s = SPx[b * 3 + ci];
      float mean = s.x * (1.f / 65536.f);
      float rstd = rsqrtf(s.y * (1.f / 65536.f) - mean * mean + INORM_EPS);
      out[ci] = (f16)((x[((size_t)b * 3 + ci) * 65536 + ir * 256 + ic] - mean) * rstd);
    }
  }
  *(f16x4*)(xP + ((size_t)b * 68644 + u) * 4) = out;
}

// ---------------- MFMA 3x3 conv, norm+relu fused into A-load --------------
// SKIP: 0 none, 1 identity add (pair layout), 2 fused 1x1 s2 projection
template <int WIN, int STRIDE, int SKIP>
__global__ __launch_bounds__(256) void conv3n(
    const f16* __restrict__ Rin, const float2* __restrict__ SPin, float inv_hw,
    const f16* __restrict__ wp, const float* __restrict__ bias,
    const float* __restrict__ bias2, const f16* __restrict__ skip,
    const f16* __restrict__ wps, f16* __restrict__ Rout,
    float2* __restrict__ ostats) {
  constexpr int WOUT = WIN / STRIDE;
  constexpr int TPR = WOUT / 16;
  constexpr int RPB = (WOUT >= 32) ? 2 : 4;
  constexpr int UNITS = TPR * RPB;
  constexpr int U = UNITS / 4;  // 1 or 2 units per wave
  const int t = threadIdx.x, w = t >> 6, l = t & 63;
  const int n = l & 15, q = l >> 4;
  const int b = blockIdx.z;
  const int yb = blockIdx.x * RPB;
  const f16* Rb = Rin + (size_t)b * WIN * WIN * 32;

  // per-lane A-slot (q*8+j) norm constants (slot-indexed stats)
  f16x8 sc, sh;
#pragma unroll
  for (int j = 0; j < 8; j++) {
    float2 s = SPin[b * 32 + q * 8 + j];
    float mean = s.x * inv_hw;
    float rstd = rsqrtf(s.y * inv_hw - mean * mean + INORM_EPS);
    sc[j] = (f16)rstd;
    sh[j] = (f16)(-mean * rstd);
  }

  f16x8 wf[18];
#pragma unroll
  for (int i = 0; i < 18; i++) wf[i] = *(const f16x8*)(wp + i * 512 + l * 8);
  f16x8 wsf0, wsf1;
  if (SKIP == 2) {
    wsf0 = *(const f16x8*)(wps + l * 8);
    wsf1 = *(const f16x8*)(wps + 512 + l * 8);
  }
  float b0 = bias[n], b1 = bias[16 + n];
  if (SKIP == 2) { b0 += bias2[n]; b1 += bias2[16 + n]; }

  f16* ro = Rout + (size_t)b * WOUT * WOUT * 32;
  const f16* sb = skip ? skip + (size_t)b * (SKIP == 2 ? 4 : 1) * WOUT * WOUT * 32 : nullptr;
  float sm0 = 0.f, sq0 = 0.f, sm1 = 0.f, sq1 = 0.f;

  auto load_u = [&](int u, f16x8* a) {
    int ty = u / TPR, tx = u % TPR;
    int y = yb + ty;
#pragma unroll
    for (int kx = 0; kx < 3; kx++) {
      int gx = STRIDE * ((tx << 4) + n) + kx - 1;
      int gxc = min(max(gx, 0), WIN - 1);
#pragma unroll
      for (int ky = 0; ky < 3; ky++) {
        int gy = STRIDE * y + ky - 1;
        int gyc = min(max(gy, 0), WIN - 1);
        a[ky * 3 + kx] = *(const f16x8*)(Rb + ((size_t)gyc * WIN + gxc) * 32 + q * 8);
      }
    }
  };
  auto compute_u = [&](int u, f16x8* a) {
    int ty = u / TPR, tx = u % TPR;
    int y = yb + ty, x0 = tx << 4;
    // norm + relu + boundary mask
#pragma unroll
    for (int kx = 0; kx < 3; kx++) {
      int gx = STRIDE * ((tx << 4) + n) + kx - 1;
      bool okx = (unsigned)gx < (unsigned)WIN;
#pragma unroll
      for (int ky = 0; ky < 3; ky++) {
        int gy = STRIDE * y + ky - 1;
        bool ok = okx && ((unsigned)gy < (unsigned)WIN);
        f16x8 v = a[ky * 3 + kx] * sc + sh;
#pragma unroll
        for (int e = 0; e < 8; e++) v[e] = v[e] > (f16)0 ? v[e] : (f16)0;
        f16x8 z = {};
        a[ky * 3 + kx] = ok ? v : z;
      }
    }
    f32x4 acc0 = {0.f, 0.f, 0.f, 0.f}, acc1 = {0.f, 0.f, 0.f, 0.f};
#pragma unroll
    for (int p = 0; p < 9; p++) {
      acc0 = __builtin_amdgcn_mfma_f32_16x16x32_f16(a[p], wf[2 * p], acc0, 0, 0, 0);
      acc1 = __builtin_amdgcn_mfma_f32_16x16x32_f16(a[p], wf[2 * p + 1], acc1, 0, 0, 0);
    }
    if (SKIP == 2) {
      const int Ws = 2 * WOUT;
      f16x8 as = *(const f16x8*)(sb + ((size_t)(2 * y) * Ws + 2 * (x0 + n)) * 32 + q * 8);
      acc0 = __builtin_amdgcn_mfma_f32_16x16x32_f16(as, wsf0, acc0, 0, 0, 0);
      acc1 = __builtin_amdgcn_mfma_f32_16x16x32_f16(as, wsf1, acc1, 0, 0, 0);
    }
#pragma unroll
    for (int r = 0; r < 4; r++) {
      size_t px = (size_t)y * WOUT + x0 + q * 4 + r;
      float v0 = acc0[r] + b0;
      float v1 = acc1[r] + b1;
      if (SKIP == 1) {
        f16x2 sv = *(const f16x2*)(sb + px * 32 + 2 * n);
        v0 += (float)sv[0];
        v1 += (float)sv[1];
      }
      f16x2 ov;
      ov[0] = (f16)v0;
      ov[1] = (f16)v1;
      *(f16x2*)(ro + px * 32 + 2 * n) = ov;
      sm0 += v0; sq0 += v0 * v0;
      sm1 += v1; sq1 += v1 * v1;
    }
  };

  f16x8 a0[9], a1[9];
  load_u(w, a0);
  if (U >= 2) load_u(w + 4, a1);
  compute_u(w, a0);
  if (U >= 2) compute_u(w + 4, a1);

  if (ostats) {
    sm0 += __shfl_xor(sm0, 16); sm0 += __shfl_xor(sm0, 32);
    sq0 += __shfl_xor(sq0, 16); sq0 += __shfl_xor(sq0, 32);
    sm1 += __shfl_xor(sm1, 16); sm1 += __shfl_xor(sm1, 32);
    sq1 += __shfl_xor(sq1, 16); sq1 += __shfl_xor(sq1, 32);
    if (l < 16) {  // slot-indexed stats: acc0 -> slot 2n, acc1 -> slot 2n+1
      atomicAdd(&ostats[b * 32 + 2 * n].x, sm0);
      atomicAdd(&ostats[b * 32 + 2 * n].y, sq0);
      atomicAdd(&ostats[b * 32 + 2 * n + 1].x, sm1);
      atomicAdd(&ostats[b * 32 + 2 * n + 1].y, sq1);
    }
  }
}

// ---------------- MFMA 7x7 s2 conv1: 1 output row/block, 2 units/wave -----
__global__ __launch_bounds__(256) void conv7(
    const f16* __restrict__ xP, const f16* __restrict__ wp,
    const float* __restrict__ bias, f16* __restrict__ Rout,
    float2* __restrict__ ostats) {
  const int t = threadIdx.x, w = t >> 6, l = t & 63;
  const int n = l & 15, q = l >> 4;
  const int b = blockIdx.z;
  const int y = blockIdx.x;
  const f16* Xb = xP + (size_t)b * 68644 * 4;
  f16x8 wf[14];
#pragma unroll
  for (int i = 0; i < 14; i++) wf[i] = *(const f16x8*)(wp + i * 512 + l * 8);
  float b0 = bias[n], b1 = bias[16 + n];
  float sm0 = 0.f, sq0 = 0.f, sm1 = 0.f, sq1 = 0.f;
  f16* ro = Rout + (size_t)b * 16384 * 32;

  auto load_u = [&](int u, f16x8* a) {
    int x0 = u * 16;
#pragma unroll
    for (int ky = 0; ky < 7; ky++)
      a[ky] = *(const f16x8*)(Xb + ((size_t)(2 * y + ky) * 262 + 2 * (x0 + n) + 2 * q) * 4);
  };
  auto compute_u = [&](int u, f16x8* a) {
    int x0 = u * 16;
    f32x4 acc0 = {0.f, 0.f, 0.f, 0.f}, acc1 = {0.f, 0.f, 0.f, 0.f};
#pragma unroll
    for (int ky = 0; ky < 7; ky++) {
      acc0 = __builtin_amdgcn_mfma_f32_16x16x32_f16(a[ky], wf[2 * ky], acc0, 0, 0, 0);
      acc1 = __builtin_amdgcn_mfma_f32_16x16x32_f16(a[ky], wf[2 * ky + 1], acc1, 0, 0, 0);
    }
#pragma unroll
    for (int r = 0; r < 4; r++) {
      size_t px = (size_t)y * 128 + x0 + q * 4 + r;
      float v0 = acc0[r] + b0;
      float v1 = acc1[r] + b1;
      f16x2 ov;
      ov[0] = (f16)v0;
      ov[1] = (f16)v1;
      *(f16x2*)(ro + px * 32 + 2 * n) = ov;
      sm0 += v0; sq0 += v0 * v0;
      sm1 += v1; sq1 += v1 * v1;
    }
  };

  f16x8 a0[7], a1[7];
  load_u(w, a0);
  load_u(w + 4, a1);
  compute_u(w, a0);
  compute_u(w + 4, a1);

  sm0 += __shfl_xor(sm0, 16); sm0 += __shfl_xor(sm0, 32);
  sq0 += __shfl_xor(sq0, 16); sq0 += __shfl_xor(sq0, 32);
  sm1 += __shfl_xor(sm1, 16); sm1 += __shfl_xor(sm1, 32);
  sq1 += __shfl_xor(sq1, 16); sq1 += __shfl_xor(sq1, 32);
  if (l < 16) {
    atomicAdd(&ostats[b * 32 + 2 * n].x, sm0);
    atomicAdd(&ostats[b * 32 + 2 * n].y, sq0);
    atomicAdd(&ostats[b * 32 + 2 * n + 1].x, sm1);
    atomicAdd(&ostats[b * 32 + 2 * n + 1].y, sq1);
  }
}

// ---------------- tail stage 1: gates G[o][b] -----------------------------
__global__ __launch_bounds__(256) void gates_kernel(
    const float* __restrict__ text, const float* __restrict__ attn_w,
    const float* __restrict__ attn_b, float* __restrict__ G) {
  __shared__ float s_text[64 * 257];
  __shared__ float s_w[16 * 256];
  const int t = threadIdx.x, wv = t >> 6, lane = t & 63;
  const int o0 = blockIdx.x * 16;
  for (int d = t; d < 16384; d += 256) {
    int b = d >> 8, k = d & 255;
    s_text[b * 257 + k] = text[d];
  }
  for (int d = t; d < 4096; d += 256) s_w[d] = attn_w[(size_t)o0 * 256 + d];
  __syncthreads();
  float acc[4];
#pragma unroll
  for (int j = 0; j < 4; j++) acc[j] = attn_b[o0 + wv * 4 + j];
  for (int k = 0; k < 256; k++) {
    float tv = s_text[lane * 257 + k];
#pragma unroll
    for (int j = 0; j < 4; j++) acc[j] = fmaf(s_w[(wv * 4 + j) * 256 + k], tv, acc[j]);
  }
#pragma unroll
  for (int j = 0; j < 4; j++) {
    int o = o0 + wv * 4 + j;
    G[o * 64 + lane] = 1.f / (1.f + __expf(-acc[j]));
  }
}

// ---------------- tail stage 2: scores -> softmax -> amapT ----------------
// channel-slot permutation is irrelevant here (softmax+sum over channels)
__global__ __launch_bounds__(256) void scores_kernel(
    const f16* __restrict__ feat, const float* __restrict__ G,
    float* __restrict__ amapT) {
  __shared__ float s_feat[256 * 33];
  __shared__ float s_gate[1280];
  __shared__ float s_scores[5 * 32];
  __shared__ float s_probs[5 * 32];
  const int b = blockIdx.x;
  const int t = threadIdx.x;

  for (int i = t; i < 8192; i += 256)
    s_feat[(i >> 5) * 33 + (i & 31)] = (float)feat[(size_t)b * 8192 + i];
  for (int i = t; i < 1280; i += 256) s_gate[i] = G[i * 64 + b];
  __syncthreads();

  if (t < 160) {
    int h = t >> 5, c = t & 31;
    float acc = 0.f;
    for (int ij = 0; ij < 256; ij++) acc += s_gate[h * 256 + ij] * s_feat[ij * 33 + c];
    s_scores[t] = acc;
  }
  __syncthreads();

  if (t < 5) {
    float mx = -1e30f;
    for (int c = 0; c < 32; c++) mx = fmaxf(mx, s_scores[t * 32 + c]);
    float sum = 0.f;
    for (int c = 0; c < 32; c++) {
      float e = __expf(s_scores[t * 32 + c] - mx);
      s_probs[t * 32 + c] = e;
      sum += e;
    }
    float inv = 1.f / sum;
    for (int c = 0; c < 32; c++) s_probs[t * 32 + c] *= inv;
  }
  __syncthreads();

  for (int h = 0; h < 5; h++) {
    float acc = 0.f;
    for (int c = 0; c < 32; c++) acc += s_probs[h * 32 + c] * s_feat[t * 33 + c];
    amapT[(h * 256 + t) * 64 + b] = acc;
  }
}

// ---------------- tail stage 3: final linear ------------------------------
__global__ __launch_bounds__(256) void final_kernel(
    const float* __restrict__ amapT, const float* __restrict__ final_w,
    const float* __restrict__ final_b, float* __restrict__ out) {
  __shared__ float s_w[8 * 1280];
  const int t = threadIdx.x, wv = t >> 6, lane = t & 63;
  const int e0 = blockIdx.x * 8;
  for (int d = t; d < 10240; d += 256) s_w[d] = final_w[(size_t)e0 * 1280 + d];
  __syncthreads();
  float acc0 = final_b[e0 + wv * 2];
  float acc1 = final_b[e0 + wv * 2 + 1];
  for (int k = 0; k < 1280; k++) {
    float av = amapT[k * 64 + lane];
    acc0 = fmaf(s_w[(wv * 2) * 1280 + k], av, acc0);
    acc1 = fmaf(s_w[(wv * 2 + 1) * 1280 + k], av, acc1);
  }
  out[(size_t)lane * 512 + e0 + wv * 2] = acc0;
  out[(size_t)lane * 512 + e0 + wv * 2 + 1] = acc1;
}

// -------------------------------------------------------------------------
extern "C" void kernel_launch(void* const* d_in, const int* in_sizes, int n_in,
                              void* d_out, int out_size, void* d_ws, size_t ws_size,
                              hipStream_t stream) {
  (void)in_sizes; (void)n_in; (void)out_size; (void)ws_size;
  const float* x       = (const float*)d_in[0];
  const float* text    = (const float*)d_in[1];
  const float* conv1_w = (const float*)d_in[2];
  const float* conv1_b = (const float*)d_in[3];
  const float* rbs_w1  = (const float*)d_in[4];
  const float* rbs_b1  = (const float*)d_in[5];
  const float* rbs_w2  = (const float*)d_in[6];
  const float* rbs_b2  = (const float*)d_in[7];
  const float* rbs_ws  = (const float*)d_in[8];
  const float* rbs_bs  = (const float*)d_in[9];
  const float* rb_w1   = (const float*)d_in[10];
  const float* rb_b1   = (const float*)d_in[11];
  const float* rb_w2   = (const float*)d_in[12];
  const float* rb_b2   = (const float*)d_in[13];
  const float* attn_w  = (const float*)d_in[14];
  const float* attn_b  = (const float*)d_in[15];
  const float* final_w = (const float*)d_in[16];
  const float* final_b = (const float*)d_in[17];
  float* out = (float*)d_out;

  char* wsb = (char*)d_ws;
  f16*   xP   = (f16*)(wsb + 0);              // 35,145,728
  f16*   R128 = (f16*)(wsb + 35145728);       // 67,108,864
  f16*   R64a = (f16*)(wsb + 102254592);      // 16,777,216
  f16*   R64b = (f16*)(wsb + 119031808);
  f16*   R64c = (f16*)(wsb + 135809024);
  f16*   R32a = (f16*)(wsb + 152586240);      // 4,194,304
  f16*   R32b = (f16*)(wsb + 156780544);
  f16*   R32c = (f16*)(wsb + 160974848);
  f16*   R16a = (f16*)(wsb + 165169152);      // 1,048,576
  f16*   R16b = (f16*)(wsb + 166217728);
  float2* SP  = (float2*)(wsb + 167266304);   // 10*2048 float2
  float2* SPx = (float2*)(wsb + 167430144);   // 192 float2
  f16*   wp3  = (f16*)(wsb + 167431680);      // 10*9216
  f16*   wp1  = (f16*)(wsb + 167616000);      // 3*1024
  f16*   wp7  = (f16*)(wsb + 167622144);      // 7168
  float* G     = (float*)(wsb + 167636480);   // 1280*64
  float* amapT = (float*)(wsb + 167964160);   // 1280*64
  float2* SP0 = SP + 0 * 2048;
  float2* SP1 = SP + 1 * 2048;
  float2* SP2 = SP + 2 * 2048;
  float2* SP3 = SP + 3 * 2048;
  float2* SP4 = SP + 4 * 2048;
  float2* SP5 = SP + 5 * 2048;
  float2* SP6 = SP + 6 * 2048;
  float2* SP7 = SP + 7 * 2048;
  float2* SP8 = SP + 8 * 2048;
  float2* SP9 = SP + 9 * 2048;

  // prep (merged) + input stats + input pack
  prep<<<480, 256, 0, stream>>>(rbs_w1, rbs_w2, rb_w1, rb_w2, rbs_ws, conv1_w,
                                SP, wp3, wp1, wp7);
  stats_raw<<<192, 256, 0, stream>>>(x, SPx, 65536);
  packx<<<dim3(269, 1, 64), 256, 0, stream>>>(x, SPx, xP);

  // conv1: 7x7 s2, 3->32, 256^2 -> 128^2
  conv7<<<dim3(128, 1, 64), 256, 0, stream>>>(xP, wp7, conv1_b, R128, SP0);

  // rbs0: 128^2 -> 64^2
  conv3n<128, 2, 0><<<dim3(32, 1, 64), 256, 0, stream>>>(
      R128, SP0, 1.f / 16384.f, wp3, rbs_b1, nullptr, nullptr, nullptr, R64a, SP1);
  conv3n<64, 1, 2><<<dim3(32, 1, 64), 256, 0, stream>>>(
      R64a, SP1, 1.f / 4096.f, wp3 + 3 * 9216, rbs_b2, rbs_bs, R128, wp1, R64b, SP2);

  // rb0: 64^2 plain resblock (identity = R64b)
  conv3n<64, 1, 0><<<dim3(32, 1, 64), 256, 0, stream>>>(
      R64b, SP2, 1.f / 4096.f, wp3 + 6 * 9216, rb_b1, nullptr, nullptr, nullptr, R64c, SP3);
  conv3n<64, 1, 1><<<dim3(32, 1, 64), 256, 0, stream>>>(
      R64c, SP3, 1.f / 4096.f, wp3 + 8 * 9216, rb_b2, nullptr, R64b, nullptr, R64a, SP4);

  // rbs1: 64^2 -> 32^2 (skip src = R64a)
  conv3n<64, 2, 0><<<dim3(16, 1, 64), 256, 0, stream>>>(
      R64a, SP4, 1.f / 4096.f, wp3 + 1 * 9216, rbs_b1 + 32, nullptr, nullptr, nullptr, R32a, SP5);
  conv3n<32, 1, 2><<<dim3(16, 1, 64), 256, 0, stream>>>(
      R32a, SP5, 1.f / 1024.f, wp3 + 4 * 9216, rbs_b2 + 32, rbs_bs + 32, R64a, wp1 + 1024, R32b, SP6);

  // rb1: 32^2 plain resblock (identity = R32b)
  conv3n<32, 1, 0><<<dim3(16, 1, 64), 256, 0, stream>>>(
      R32b, SP6, 1.f / 1024.f, wp3 + 7 * 9216, rb_b1 + 32, nullptr, nullptr, nullptr, R32c, SP7);
  conv3n<32, 1, 1><<<dim3(16, 1, 64), 256, 0, stream>>>(
      R32c, SP7, 1.f / 1024.f, wp3 + 9 * 9216, rb_b2 + 32, nullptr, R32b, nullptr, R32a, SP8);

  // rbs2: 32^2 -> 16^2 (skip src = R32a)
  conv3n<32, 2, 0><<<dim3(4, 1, 64), 256, 0, stream>>>(
      R32a, SP8, 1.f / 1024.f, wp3 + 2 * 9216, rbs_b1 + 64, nullptr, nullptr, nullptr, R16a, SP9);
  conv3n<16, 1, 2><<<dim3(4, 1, 64), 256, 0, stream>>>(
      R16a, SP9, 1.f / 256.f, wp3 + 5 * 9216, rbs_b2 + 64, rbs_bs + 64, R32a, wp1 + 2048, R16b, nullptr);

  // attention tail
  gates_kernel<<<80, 256, 0, stream>>>(text, attn_w, attn_b, G);
  scores_kernel<<<64, 256, 0, stream>>>(R16b, G, amapT);
  final_kernel<<<64, 256, 0, stream>>>(amapT, final_w, final_b, out);
}

// Round 7
// 432.077 us; speedup vs baseline: 1.7000x; 1.7000x over previous
//
#include <hip/hip_runtime.h>
#include <cstdint>
#include <cstddef>

#define INORM_EPS 1e-5f

typedef _Float16 f16;
typedef f16 f16x8 __attribute__((ext_vector_type(8)));
typedef f16 f16x4 __attribute__((ext_vector_type(4)));
typedef float f32x4 __attribute__((ext_vector_type(4)));

// ---------------- one merged prep kernel ----------------------------------
__global__ __launch_bounds__(256) void prep(
    const float* __restrict__ rbs_w1, const float* __restrict__ rbs_w2,
    const float* __restrict__ rb_w1, const float* __restrict__ rb_w2,
    const float* __restrict__ rbs_ws, const float* __restrict__ conv1_w,
    float2* __restrict__ SP, f16* __restrict__ wp3, f16* __restrict__ wp1,
    f16* __restrict__ wp7) {
  int i = blockIdx.x * 256 + threadIdx.x;
  if (i < 20480) { SP[i] = make_float2(0.f, 0.f); return; }
  i -= 20480;
  if (i < 92160) {  // [mat][9 taps][2 halves][64 lanes][8] ; B-frag layout
    int mat = i / 9216, r = i % 9216;
    int p = r >> 10, f = (r >> 9) & 1, l = (r >> 3) & 63, j = r & 7;
    int co = f * 16 + (l & 15), ci = (l >> 4) * 8 + j;
    const float* src; int m;
    if (mat < 3) { src = rbs_w1; m = mat; }
    else if (mat < 6) { src = rbs_w2; m = mat - 3; }
    else if (mat < 8) { src = rb_w1; m = mat - 6; }
    else { src = rb_w2; m = mat - 8; }
    wp3[i] = (f16)src[m * 9216 + co * 288 + ci * 9 + p];
    return;
  }
  i -= 92160;
  if (i < 3072) {
    int mat = i / 1024, r = i % 1024;
    int f = r >> 9, l = (r >> 3) & 63, j = r & 7;
    wp1[i] = (f16)rbs_ws[mat * 1024 + (f * 16 + (l & 15)) * 32 + (l >> 4) * 8 + j];
    return;
  }
  i -= 3072;
  int ky = i >> 10, f = (i >> 9) & 1, l = (i >> 3) & 63, j = i & 7;
  int k = (l >> 4) * 8 + j, kx = k >> 2, ci = k & 3;
  float v = 0.f;
  if (kx < 7 && ci < 3) v = conv1_w[(f * 16 + (l & 15)) * 147 + ci * 49 + ky * 7 + kx];
  wp7[i] = (f16)v;
}

// ---------------- raw (sum, sumsq) stats for fp32 input x -----------------
__global__ __launch_bounds__(256) void stats_raw(const float* __restrict__ in,
                                                 float2* __restrict__ st, int HW) {
  const float4* p = (const float4*)(in + (size_t)blockIdx.x * HW);
  float s = 0.f, ss = 0.f;
  int n4 = HW >> 2;
  for (int i = threadIdx.x; i < n4; i += 256) {
    float4 v = p[i];
    s += v.x + v.y + v.z + v.w;
    ss += v.x * v.x + v.y * v.y + v.z * v.z + v.w * v.w;
  }
  __shared__ float r0[256], r1[256];
  r0[threadIdx.x] = s;
  r1[threadIdx.x] = ss;
  __syncthreads();
  for (int off = 128; off > 0; off >>= 1) {
    if ((int)threadIdx.x < off) {
      r0[threadIdx.x] += r0[threadIdx.x + off];
      r1[threadIdx.x] += r1[threadIdx.x + off];
    }
    __syncthreads();
  }
  if (threadIdx.x == 0) st[blockIdx.x] = make_float2(r0[0], r1[0]);
}

// ---- pack x: fp32 NCHW -> normed padded f16 [64][262][262][4] ------------
__global__ __launch_bounds__(256) void packx(const float* __restrict__ x,
                                             const float2* __restrict__ SPx,
                                             f16* __restrict__ xP) {
  int u = blockIdx.x * 256 + threadIdx.x;
  if (u >= 262 * 262) return;
  int b = blockIdx.z;
  int r = u / 262, c = u % 262;
  f16x4 out;
  out[0] = (f16)0; out[1] = (f16)0; out[2] = (f16)0; out[3] = (f16)0;
  if (r >= 3 && r < 259 && c >= 3 && c < 259) {
    int ir = r - 3, ic = c - 3;
#pragma unroll
    for (int ci = 0; ci < 3; ci++) {
      float2 s = SPx[b * 3 + ci];
      float mean = s.x * (1.f / 65536.f);
      float rstd = rsqrtf(s.y * (1.f / 65536.f) - mean * mean + INORM_EPS);
      out[ci] = (f16)((x[((size_t)b * 3 + ci) * 65536 + ir * 256 + ic] - mean) * rstd);
    }
  }
  *(f16x4*)(xP + ((size_t)b * 68644 + u) * 4) = out;
}

// ---------------- MFMA 3x3 conv, norm+relu fused into A-load --------------
// Input: RAW f16 NHWC map + fp32 raw stats. SKIP: 0 none, 1 identity add,
// 2 fused 1x1 stride-2 projection (raw input map, no norm).
template <int WIN, int STRIDE, int SKIP>
__global__ __launch_bounds__(256) void conv3n(
    const f16* __restrict__ Rin, const float2* __restrict__ SPin, float inv_hw,
    const f16* __restrict__ wp, const float* __restrict__ bias,
    const float* __restrict__ bias2, const f16* __restrict__ skip,
    const f16* __restrict__ wps, f16* __restrict__ Rout,
    float2* __restrict__ ostats) {
  constexpr int WOUT = WIN / STRIDE;
  constexpr int TPR = WOUT / 16;
  constexpr int RPB = (WOUT >= 32) ? 4 : 8;
  constexpr int UNITS = TPR * RPB;
  constexpr int U = UNITS / 4;
  const int t = threadIdx.x, w = t >> 6, l = t & 63;
  const int n = l & 15, q = l >> 4;
  const int b = blockIdx.z;
  const int yb = blockIdx.x * RPB;
  const f16* Rb = Rin + (size_t)b * WIN * WIN * 32;

  // per-lane A-channel (q*8+j) norm constants
  f16x8 sc, sh;
#pragma unroll
  for (int j = 0; j < 8; j++) {
    float2 s = SPin[b * 32 + q * 8 + j];
    float mean = s.x * inv_hw;
    float rstd = rsqrtf(s.y * inv_hw - mean * mean + INORM_EPS);
    sc[j] = (f16)rstd;
    sh[j] = (f16)(-mean * rstd);
  }

  f16x8 wf[18];
#pragma unroll
  for (int i = 0; i < 18; i++) wf[i] = *(const f16x8*)(wp + i * 512 + l * 8);
  f16x8 wsf0, wsf1;
  if (SKIP == 2) {
    wsf0 = *(const f16x8*)(wps + l * 8);
    wsf1 = *(const f16x8*)(wps + 512 + l * 8);
  }
  float b0 = bias[n], b1 = bias[16 + n];
  if (SKIP == 2) { b0 += bias2[n]; b1 += bias2[16 + n]; }

  f16* ro = Rout + (size_t)b * WOUT * WOUT * 32;
  const f16* sb = skip ? skip + (size_t)b * (SKIP == 2 ? 4 : 1) * WOUT * WOUT * 32 : nullptr;

  auto load_u = [&](int u, f16x8* a) {
    int ty = u / TPR, tx = u % TPR;
    int y = yb + ty;
#pragma unroll
    for (int kx = 0; kx < 3; kx++) {
      int gx = STRIDE * ((tx << 4) + n) + kx - 1;
      int gxc = min(max(gx, 0), WIN - 1);
#pragma unroll
      for (int ky = 0; ky < 3; ky++) {
        int gy = STRIDE * y + ky - 1;
        int gyc = min(max(gy, 0), WIN - 1);
        a[ky * 3 + kx] = *(const f16x8*)(Rb + ((size_t)gyc * WIN + gxc) * 32 + q * 8);
      }
    }
  };
  auto norm_u = [&](int u, f16x8* a) {
    int ty = u / TPR, tx = u % TPR;
    int y = yb + ty;
#pragma unroll
    for (int kx = 0; kx < 3; kx++) {
      int gx = STRIDE * ((tx << 4) + n) + kx - 1;
      bool okx = (unsigned)gx < (unsigned)WIN;
#pragma unroll
      for (int ky = 0; ky < 3; ky++) {
        int gy = STRIDE * y + ky - 1;
        bool ok = okx && ((unsigned)gy < (unsigned)WIN);
        f16x8 v = a[ky * 3 + kx] * sc + sh;
#pragma unroll
        for (int e = 0; e < 8; e++) v[e] = v[e] > (f16)0 ? v[e] : (f16)0;
        f16x8 z = {};
        a[ky * 3 + kx] = ok ? v : z;
      }
    }
  };

  float sm0 = 0.f, sq0 = 0.f, sm1 = 0.f, sq1 = 0.f;
  f16x8 araw[9], anxt[9];
  load_u(w, araw);
#pragma unroll
  for (int i = 0; i < U; i++) {
    int u = w + 4 * i;
    if (i + 1 < U) load_u(u + 4, anxt);
    norm_u(u, araw);
    int ty = u / TPR, tx = u % TPR;
    int y = yb + ty, x0 = tx << 4;
    f32x4 acc0 = {0.f, 0.f, 0.f, 0.f}, acc1 = {0.f, 0.f, 0.f, 0.f};
#pragma unroll
    for (int p = 0; p < 9; p++) {
      acc0 = __builtin_amdgcn_mfma_f32_16x16x32_f16(araw[p], wf[2 * p], acc0, 0, 0, 0);
      acc1 = __builtin_amdgcn_mfma_f32_16x16x32_f16(araw[p], wf[2 * p + 1], acc1, 0, 0, 0);
    }
    if (SKIP == 2) {
      const int Ws = 2 * WOUT;
      f16x8 as = *(const f16x8*)(sb + ((size_t)(2 * y) * Ws + 2 * (x0 + n)) * 32 + q * 8);
      acc0 = __builtin_amdgcn_mfma_f32_16x16x32_f16(as, wsf0, acc0, 0, 0, 0);
      acc1 = __builtin_amdgcn_mfma_f32_16x16x32_f16(as, wsf1, acc1, 0, 0, 0);
    }
#pragma unroll
    for (int r = 0; r < 4; r++) {
      size_t px = (size_t)y * WOUT + x0 + q * 4 + r;
      float v0 = acc0[r] + b0;
      float v1 = acc1[r] + b1;
      if (SKIP == 1) {
        v0 += (float)sb[px * 32 + n];
        v1 += (float)sb[px * 32 + 16 + n];
      }
      ro[px * 32 + n] = (f16)v0;
      ro[px * 32 + 16 + n] = (f16)v1;
      sm0 += v0; sq0 += v0 * v0;
      sm1 += v1; sq1 += v1 * v1;
    }
#pragma unroll
    for (int p = 0; p < 9; p++) araw[p] = anxt[p];
  }
  if (ostats) {
    sm0 += __shfl_xor(sm0, 16); sm0 += __shfl_xor(sm0, 32);
    sq0 += __shfl_xor(sq0, 16); sq0 += __shfl_xor(sq0, 32);
    sm1 += __shfl_xor(sm1, 16); sm1 += __shfl_xor(sm1, 32);
    sq1 += __shfl_xor(sq1, 16); sq1 += __shfl_xor(sq1, 32);
    if (l < 16) {
      atomicAdd(&ostats[b * 32 + n].x, sm0);
      atomicAdd(&ostats[b * 32 + n].y, sq0);
      atomicAdd(&ostats[b * 32 + 16 + n].x, sm1);
      atomicAdd(&ostats[b * 32 + 16 + n].y, sq1);
    }
  }
}

// ---------------- MFMA 7x7 s2 conv1: 4 output rows/block, 8 units/wave ----
// Rolling depth-1 prefetch; bigger blocks amortize the 14-frag weight load
// and improve input-row L1/L2 reuse (R6 showed smaller blocks regress).
__global__ __launch_bounds__(256) void conv7(
    const f16* __restrict__ xP, const f16* __restrict__ wp,
    const float* __restrict__ bias, f16* __restrict__ Rout,
    float2* __restrict__ ostats) {
  const int t = threadIdx.x, w = t >> 6, l = t & 63;
  const int n = l & 15, q = l >> 4;
  const int b = blockIdx.z;
  const int yb = blockIdx.x * 4;
  const f16* Xb = xP + (size_t)b * 68644 * 4;
  f16x8 wf[14];
#pragma unroll
  for (int i = 0; i < 14; i++) wf[i] = *(const f16x8*)(wp + i * 512 + l * 8);
  float b0 = bias[n], b1 = bias[16 + n];
  float sm0 = 0.f, sq0 = 0.f, sm1 = 0.f, sq1 = 0.f;
  f16* ro = Rout + (size_t)b * 16384 * 32;

  auto load_u = [&](int u, f16x8* a) {
    int ty = u >> 3, tx = u & 7;
    int y = yb + ty, x0 = tx * 16;
#pragma unroll
    for (int ky = 0; ky < 7; ky++)
      a[ky] = *(const f16x8*)(Xb + ((size_t)(2 * y + ky) * 262 + 2 * (x0 + n) + 2 * q) * 4);
  };

  f16x8 araw[7], anxt[7];
  load_u(w, araw);
#pragma unroll
  for (int i = 0; i < 8; i++) {
    int u = w + 4 * i;
    if (i < 7) load_u(u + 4, anxt);
    int ty = u >> 3, tx = u & 7;
    int y = yb + ty, x0 = tx * 16;
    f32x4 acc0 = {0.f, 0.f, 0.f, 0.f}, acc1 = {0.f, 0.f, 0.f, 0.f};
#pragma unroll
    for (int ky = 0; ky < 7; ky++) {
      acc0 = __builtin_amdgcn_mfma_f32_16x16x32_f16(araw[ky], wf[2 * ky], acc0, 0, 0, 0);
      acc1 = __builtin_amdgcn_mfma_f32_16x16x32_f16(araw[ky], wf[2 * ky + 1], acc1, 0, 0, 0);
    }
#pragma unroll
    for (int r = 0; r < 4; r++) {
      size_t px = (size_t)y * 128 + x0 + q * 4 + r;
      float v0 = acc0[r] + b0;
      float v1 = acc1[r] + b1;
      ro[px * 32 + n] = (f16)v0;
      ro[px * 32 + 16 + n] = (f16)v1;
      sm0 += v0; sq0 += v0 * v0;
      sm1 += v1; sq1 += v1 * v1;
    }
#pragma unroll
    for (int ky = 0; ky < 7; ky++) araw[ky] = anxt[ky];
  }
  sm0 += __shfl_xor(sm0, 16); sm0 += __shfl_xor(sm0, 32);
  sq0 += __shfl_xor(sq0, 16); sq0 += __shfl_xor(sq0, 32);
  sm1 += __shfl_xor(sm1, 16); sm1 += __shfl_xor(sm1, 32);
  sq1 += __shfl_xor(sq1, 16); sq1 += __shfl_xor(sq1, 32);
  if (l < 16) {
    atomicAdd(&ostats[b * 32 + n].x, sm0);
    atomicAdd(&ostats[b * 32 + n].y, sq0);
    atomicAdd(&ostats[b * 32 + 16 + n].x, sm1);
    atomicAdd(&ostats[b * 32 + 16 + n].y, sq1);
  }
}

// ---------------- tail stage 1: gates G[o][b] -----------------------------
__global__ __launch_bounds__(256) void gates_kernel(
    const float* __restrict__ text, const float* __restrict__ attn_w,
    const float* __restrict__ attn_b, float* __restrict__ G) {
  __shared__ float s_text[64 * 257];
  __shared__ float s_w[16 * 256];
  const int t = threadIdx.x, wv = t >> 6, lane = t & 63;
  const int o0 = blockIdx.x * 16;
  for (int d = t; d < 16384; d += 256) {
    int b = d >> 8, k = d & 255;
    s_text[b * 257 + k] = text[d];
  }
  for (int d = t; d < 4096; d += 256) s_w[d] = attn_w[(size_t)o0 * 256 + d];
  __syncthreads();
  float acc[4];
#pragma unroll
  for (int j = 0; j < 4; j++) acc[j] = attn_b[o0 + wv * 4 + j];
  for (int k = 0; k < 256; k++) {
    float tv = s_text[lane * 257 + k];
#pragma unroll
    for (int j = 0; j < 4; j++) acc[j] = fmaf(s_w[(wv * 4 + j) * 256 + k], tv, acc[j]);
  }
#pragma unroll
  for (int j = 0; j < 4; j++) {
    int o = o0 + wv * 4 + j;
    G[o * 64 + lane] = 1.f / (1.f + __expf(-acc[j]));
  }
}

// ---------------- tail stage 2: scores -> softmax -> amapT ----------------
__global__ __launch_bounds__(256) void scores_kernel(
    const f16* __restrict__ feat, const float* __restrict__ G,
    float* __restrict__ amapT) {
  __shared__ float s_feat[256 * 33];
  __shared__ float s_gate[1280];
  __shared__ float s_scores[5 * 32];
  __shared__ float s_probs[5 * 32];
  const int b = blockIdx.x;
  const int t = threadIdx.x;

  for (int i = t; i < 8192; i += 256)
    s_feat[(i >> 5) * 33 + (i & 31)] = (float)feat[(size_t)b * 8192 + i];
  for (int i = t; i < 1280; i += 256) s_gate[i] = G[i * 64 + b];
  __syncthreads();

  if (t < 160) {
    int h = t >> 5, c = t & 31;
    float acc = 0.f;
    for (int ij = 0; ij < 256; ij++) acc += s_gate[h * 256 + ij] * s_feat[ij * 33 + c];
    s_scores[t] = acc;
  }
  __syncthreads();

  if (t < 5) {
    float mx = -1e30f;
    for (int c = 0; c < 32; c++) mx = fmaxf(mx, s_scores[t * 32 + c]);
    float sum = 0.f;
    for (int c = 0; c < 32; c++) {
      float e = __expf(s_scores[t * 32 + c] - mx);
      s_probs[t * 32 + c] = e;
      sum += e;
    }
    float inv = 1.f / sum;
    for (int c = 0; c < 32; c++) s_probs[t * 32 + c] *= inv;
  }
  __syncthreads();

  for (int h = 0; h < 5; h++) {
    float acc = 0.f;
    for (int c = 0; c < 32; c++) acc += s_probs[h * 32 + c] * s_feat[t * 33 + c];
    amapT[(h * 256 + t) * 64 + b] = acc;
  }
}

// ---------------- tail stage 3: final linear ------------------------------
__global__ __launch_bounds__(256) void final_kernel(
    const float* __restrict__ amapT, const float* __restrict__ final_w,
    const float* __restrict__ final_b, float* __restrict__ out) {
  __shared__ float s_w[8 * 1280];
  const int t = threadIdx.x, wv = t >> 6, lane = t & 63;
  const int e0 = blockIdx.x * 8;
  for (int d = t; d < 10240; d += 256) s_w[d] = final_w[(size_t)e0 * 1280 + d];
  __syncthreads();
  float acc0 = final_b[e0 + wv * 2];
  float acc1 = final_b[e0 + wv * 2 + 1];
  for (int k = 0; k < 1280; k++) {
    float av = amapT[k * 64 + lane];
    acc0 = fmaf(s_w[(wv * 2) * 1280 + k], av, acc0);
    acc1 = fmaf(s_w[(wv * 2 + 1) * 1280 + k], av, acc1);
  }
  out[(size_t)lane * 512 + e0 + wv * 2] = acc0;
  out[(size_t)lane * 512 + e0 + wv * 2 + 1] = acc1;
}

// -------------------------------------------------------------------------
extern "C" void kernel_launch(void* const* d_in, const int* in_sizes, int n_in,
                              void* d_out, int out_size, void* d_ws, size_t ws_size,
                              hipStream_t stream) {
  (void)in_sizes; (void)n_in; (void)out_size; (void)ws_size;
  const float* x       = (const float*)d_in[0];
  const float* text    = (const float*)d_in[1];
  const float* conv1_w = (const float*)d_in[2];
  const float* conv1_b = (const float*)d_in[3];
  const float* rbs_w1  = (const float*)d_in[4];
  const float* rbs_b1  = (const float*)d_in[5];
  const float* rbs_w2  = (const float*)d_in[6];
  const float* rbs_b2  = (const float*)d_in[7];
  const float* rbs_ws  = (const float*)d_in[8];
  const float* rbs_bs  = (const float*)d_in[9];
  const float* rb_w1   = (const float*)d_in[10];
  const float* rb_b1   = (const float*)d_in[11];
  const float* rb_w2   = (const float*)d_in[12];
  const float* rb_b2   = (const float*)d_in[13];
  const float* attn_w  = (const float*)d_in[14];
  const float* attn_b  = (const float*)d_in[15];
  const float* final_w = (const float*)d_in[16];
  const float* final_b = (const float*)d_in[17];
  float* out = (float*)d_out;

  char* wsb = (char*)d_ws;
  f16*   xP   = (f16*)(wsb + 0);              // 35,145,728
  f16*   R128 = (f16*)(wsb + 35145728);       // 67,108,864
  f16*   R64a = (f16*)(wsb + 102254592);      // 16,777,216
  f16*   R64b = (f16*)(wsb + 119031808);
  f16*   R64c = (f16*)(wsb + 135809024);
  f16*   R32a = (f16*)(wsb + 152586240);      // 4,194,304
  f16*   R32b = (f16*)(wsb + 156780544);
  f16*   R32c = (f16*)(wsb + 160974848);
  f16*   R16a = (f16*)(wsb + 165169152);      // 1,048,576
  f16*   R16b = (f16*)(wsb + 166217728);
  float2* SP  = (float2*)(wsb + 167266304);   // 10*2048 float2
  float2* SPx = (float2*)(wsb + 167430144);   // 192 float2
  f16*   wp3  = (f16*)(wsb + 167431680);      // 10*9216
  f16*   wp1  = (f16*)(wsb + 167616000);      // 3*1024
  f16*   wp7  = (f16*)(wsb + 167622144);      // 7168
  float* G     = (float*)(wsb + 167636480);   // 1280*64
  float* amapT = (float*)(wsb + 167964160);   // 1280*64
  float2* SP0 = SP + 0 * 2048;
  float2* SP1 = SP + 1 * 2048;
  float2* SP2 = SP + 2 * 2048;
  float2* SP3 = SP + 3 * 2048;
  float2* SP4 = SP + 4 * 2048;
  float2* SP5 = SP + 5 * 2048;
  float2* SP6 = SP + 6 * 2048;
  float2* SP7 = SP + 7 * 2048;
  float2* SP8 = SP + 8 * 2048;
  float2* SP9 = SP + 9 * 2048;

  // prep (merged) + input stats + input pack
  prep<<<480, 256, 0, stream>>>(rbs_w1, rbs_w2, rb_w1, rb_w2, rbs_ws, conv1_w,
                                SP, wp3, wp1, wp7);
  stats_raw<<<192, 256, 0, stream>>>(x, SPx, 65536);
  packx<<<dim3(269, 1, 64), 256, 0, stream>>>(x, SPx, xP);

  // conv1: 7x7 s2, 3->32, 256^2 -> 128^2 (4 rows/block)
  conv7<<<dim3(32, 1, 64), 256, 0, stream>>>(xP, wp7, conv1_b, R128, SP0);

  // rbs0: 128^2 -> 64^2
  conv3n<128, 2, 0><<<dim3(16, 1, 64), 256, 0, stream>>>(
      R128, SP0, 1.f / 16384.f, wp3, rbs_b1, nullptr, nullptr, nullptr, R64a, SP1);
  conv3n<64, 1, 2><<<dim3(16, 1, 64), 256, 0, stream>>>(
      R64a, SP1, 1.f / 4096.f, wp3 + 3 * 9216, rbs_b2, rbs_bs, R128, wp1, R64b, SP2);

  // rb0: 64^2 plain resblock (identity = R64b)
  conv3n<64, 1, 0><<<dim3(16, 1, 64), 256, 0, stream>>>(
      R64b, SP2, 1.f / 4096.f, wp3 + 6 * 9216, rb_b1, nullptr, nullptr, nullptr, R64c, SP3);
  conv3n<64, 1, 1><<<dim3(16, 1, 64), 256, 0, stream>>>(
      R64c, SP3, 1.f / 4096.f, wp3 + 8 * 9216, rb_b2, nullptr, R64b, nullptr, R64a, SP4);

  // rbs1: 64^2 -> 32^2 (skip src = R64a)
  conv3n<64, 2, 0><<<dim3(8, 1, 64), 256, 0, stream>>>(
      R64a, SP4, 1.f / 4096.f, wp3 + 1 * 9216, rbs_b1 + 32, nullptr, nullptr, nullptr, R32a, SP5);
  conv3n<32, 1, 2><<<dim3(8, 1, 64), 256, 0, stream>>>(
      R32a, SP5, 1.f / 1024.f, wp3 + 4 * 9216, rbs_b2 + 32, rbs_bs + 32, R64a, wp1 + 1024, R32b, SP6);

  // rb1: 32^2 plain resblock (identity = R32b)
  conv3n<32, 1, 0><<<dim3(8, 1, 64), 256, 0, stream>>>(
      R32b, SP6, 1.f / 1024.f, wp3 + 7 * 9216, rb_b1 + 32, nullptr, nullptr, nullptr, R32c, SP7);
  conv3n<32, 1, 1><<<dim3(8, 1, 64), 256, 0, stream>>>(
      R32c, SP7, 1.f / 1024.f, wp3 + 9 * 9216, rb_b2 + 32, nullptr, R32b, nullptr, R32a, SP8);

  // rbs2: 32^2 -> 16^2 (skip src = R32a)
  conv3n<32, 2, 0><<<dim3(2, 1, 64), 256, 0, stream>>>(
      R32a, SP8, 1.f / 1024.f, wp3 + 2 * 9216, rbs_b1 + 64, nullptr, nullptr, nullptr, R16a, SP9);
  conv3n<16, 1, 2><<<dim3(2, 1, 64), 256, 0, stream>>>(
      R16a, SP9, 1.f / 256.f, wp3 + 5 * 9216, rbs_b2 + 64, rbs_bs + 64, R32a, wp1 + 2048, R16b, nullptr);

  // attention tail
  gates_kernel<<<80, 256, 0, stream>>>(text, attn_w, attn_b, G);
  scores_kernel<<<64, 256, 0, stream>>>(R16b, G, amapT);
  final_kernel<<<64, 256, 0, stream>>>(amapT, final_w, final_b, out);
}

// Round 8
// 377.127 us; speedup vs baseline: 1.9478x; 1.1457x over previous
//
#include <hip/hip_runtime.h>
#include <cstdint>
#include <cstddef>

#define INORM_EPS 1e-5f

typedef _Float16 f16;
typedef f16 f16x8 __attribute__((ext_vector_type(8)));
typedef f16 f16x4 __attribute__((ext_vector_type(4)));
typedef float f32x4 __attribute__((ext_vector_type(4)));

// ---------------- one merged prep kernel ----------------------------------
__global__ __launch_bounds__(256) void prep(
    const float* __restrict__ rbs_w1, const float* __restrict__ rbs_w2,
    const float* __restrict__ rb_w1, const float* __restrict__ rb_w2,
    const float* __restrict__ rbs_ws, const float* __restrict__ conv1_w,
    float2* __restrict__ SP, f16* __restrict__ wp3, f16* __restrict__ wp1,
    f16* __restrict__ wp7) {
  int i = blockIdx.x * 256 + threadIdx.x;
  if (i < 20480) { SP[i] = make_float2(0.f, 0.f); return; }
  i -= 20480;
  if (i < 92160) {  // [mat][9 taps][2 halves][64 lanes][8] ; B-frag layout
    int mat = i / 9216, r = i % 9216;
    int p = r >> 10, f = (r >> 9) & 1, l = (r >> 3) & 63, j = r & 7;
    int co = f * 16 + (l & 15), ci = (l >> 4) * 8 + j;
    const float* src; int m;
    if (mat < 3) { src = rbs_w1; m = mat; }
    else if (mat < 6) { src = rbs_w2; m = mat - 3; }
    else if (mat < 8) { src = rb_w1; m = mat - 6; }
    else { src = rb_w2; m = mat - 8; }
    wp3[i] = (f16)src[m * 9216 + co * 288 + ci * 9 + p];
    return;
  }
  i -= 92160;
  if (i < 3072) {
    int mat = i / 1024, r = i % 1024;
    int f = r >> 9, l = (r >> 3) & 63, j = r & 7;
    wp1[i] = (f16)rbs_ws[mat * 1024 + (f * 16 + (l & 15)) * 32 + (l >> 4) * 8 + j];
    return;
  }
  i -= 3072;
  int ky = i >> 10, f = (i >> 9) & 1, l = (i >> 3) & 63, j = i & 7;
  int k = (l >> 4) * 8 + j, kx = k >> 2, ci = k & 3;
  float v = 0.f;
  if (kx < 7 && ci < 3) v = conv1_w[(f * 16 + (l & 15)) * 147 + ci * 49 + ky * 7 + kx];
  wp7[i] = (f16)v;
}

// ---------------- raw (sum, sumsq) stats for fp32 input x -----------------
__global__ __launch_bounds__(256) void stats_raw(const float* __restrict__ in,
                                                 float2* __restrict__ st, int HW) {
  const float4* p = (const float4*)(in + (size_t)blockIdx.x * HW);
  float s = 0.f, ss = 0.f;
  int n4 = HW >> 2;
  for (int i = threadIdx.x; i < n4; i += 256) {
    float4 v = p[i];
    s += v.x + v.y + v.z + v.w;
    ss += v.x * v.x + v.y * v.y + v.z * v.z + v.w * v.w;
  }
  __shared__ float r0[256], r1[256];
  r0[threadIdx.x] = s;
  r1[threadIdx.x] = ss;
  __syncthreads();
  for (int off = 128; off > 0; off >>= 1) {
    if ((int)threadIdx.x < off) {
      r0[threadIdx.x] += r0[threadIdx.x + off];
      r1[threadIdx.x] += r1[threadIdx.x + off];
    }
    __syncthreads();
  }
  if (threadIdx.x == 0) st[blockIdx.x] = make_float2(r0[0], r1[0]);
}

// ---- pack x: fp32 NCHW -> normed padded f16 [64][262][262][4] ------------
__global__ __launch_bounds__(256) void packx(const float* __restrict__ x,
                                             const float2* __restrict__ SPx,
                                             f16* __restrict__ xP) {
  int u = blockIdx.x * 256 + threadIdx.x;
  if (u >= 262 * 262) return;
  int b = blockIdx.z;
  int r = u / 262, c = u % 262;
  f16x4 out;
  out[0] = (f16)0; out[1] = (f16)0; out[2] = (f16)0; out[3] = (f16)0;
  if (r >= 3 && r < 259 && c >= 3 && c < 259) {
    int ir = r - 3, ic = c - 3;
#pragma unroll
    for (int ci = 0; ci < 3; ci++) {
      float2 s = SPx[b * 3 + ci];
      float mean = s.x * (1.f / 65536.f);
      float rstd = rsqrtf(s.y * (1.f / 65536.f) - mean * mean + INORM_EPS);
      out[ci] = (f16)((x[((size_t)b * 3 + ci) * 65536 + ir * 256 + ic] - mean) * rstd);
    }
  }
  *(f16x4*)(xP + ((size_t)b * 68644 + u) * 4) = out;
}

// ---------------- MFMA 3x3 stride-1 conv, rolling row window --------------
// Each wave owns one column (16 px) and walks LEN consecutive rows, keeping
// a circular 3-row normalized window: 3 new frags/unit instead of 9, and
// each row is normalized once. SKIP: 0 none, 1 identity, 2 fused 1x1 s2.
template <int W, int SKIP>
__global__ __launch_bounds__(256) void conv3r(
    const f16* __restrict__ Rin, const float2* __restrict__ SPin, float inv_hw,
    const f16* __restrict__ wp, const float* __restrict__ bias,
    const float* __restrict__ bias2, const f16* __restrict__ skip,
    const f16* __restrict__ wps, f16* __restrict__ Rout,
    float2* __restrict__ ostats) {
  constexpr int TPR = W / 16;
  constexpr int RPB = 8;                 // output rows per block
  constexpr int LEN = (RPB * TPR) / 4;   // rows per wave (8 for W=64, 4 for W=32)
  const int t = threadIdx.x, w = t >> 6, l = t & 63;
  const int n = l & 15, q = l >> 4;
  const int b = blockIdx.z;
  const int tx = w % TPR;
  const int y0 = blockIdx.x * RPB + (w / TPR) * LEN;
  const int x = (tx << 4) + n;
  const f16* Rb = Rin + (size_t)b * W * W * 32;

  // per-lane A-channel (q*8+j) norm constants
  f16x8 sc, sh;
#pragma unroll
  for (int j = 0; j < 8; j++) {
    float2 s = SPin[b * 32 + q * 8 + j];
    float mean = s.x * inv_hw;
    float rstd = rsqrtf(s.y * inv_hw - mean * mean + INORM_EPS);
    sc[j] = (f16)rstd;
    sh[j] = (f16)(-mean * rstd);
  }

  f16x8 wf[18];
#pragma unroll
  for (int i = 0; i < 18; i++) wf[i] = *(const f16x8*)(wp + i * 512 + l * 8);
  f16x8 wsf0, wsf1;
  if (SKIP == 2) {
    wsf0 = *(const f16x8*)(wps + l * 8);
    wsf1 = *(const f16x8*)(wps + 512 + l * 8);
  }
  float b0 = bias[n], b1 = bias[16 + n];
  if (SKIP == 2) { b0 += bias2[n]; b1 += bias2[16 + n]; }

  f16* ro = Rout + (size_t)b * W * W * 32;
  const f16* sb = skip ? skip + (size_t)b * (SKIP == 2 ? 4 : 1) * W * W * 32 : nullptr;

  bool okc[3];
#pragma unroll
  for (int kx = 0; kx < 3; kx++) okc[kx] = (unsigned)(x + kx - 1) < (unsigned)W;

  auto rowload = [&](int gy, f16x8* dst) {
    int gyc = min(max(gy, 0), W - 1);
#pragma unroll
    for (int kx = 0; kx < 3; kx++) {
      int gxc = min(max(x + kx - 1, 0), W - 1);
      dst[kx] = *(const f16x8*)(Rb + ((size_t)gyc * W + gxc) * 32 + q * 8);
    }
  };
  auto rownorm = [&](int gy, const f16x8* src, f16x8* dst) {
    bool okr = (unsigned)gy < (unsigned)W;
#pragma unroll
    for (int kx = 0; kx < 3; kx++) {
      f16x8 v = src[kx] * sc + sh;
#pragma unroll
      for (int e = 0; e < 8; e++) v[e] = v[e] > (f16)0 ? v[e] : (f16)0;
      f16x8 z = {};
      dst[kx] = (okr && okc[kx]) ? v : z;
    }
  };

  float sm0 = 0.f, sq0 = 0.f, sm1 = 0.f, sq1 = 0.f;
  f16x8 win[9];   // [slot(0..2)][kx] ; row j lives at slot (j+1)%3
  f16x8 tmp[3], pf[3];
  // init rows j=-1,0,1 -> slots 0,1,2
#pragma unroll
  for (int jj = 0; jj < 3; jj++) {
    rowload(y0 + jj - 1, tmp);
    rownorm(y0 + jj - 1, tmp, &win[jj * 3]);
  }

#pragma unroll
  for (int i = 0; i < LEN; i++) {
    int y = y0 + i;
    if (i + 1 < LEN) rowload(y0 + i + 2, pf);   // row for next unit, in flight
    f32x4 acc0 = {0.f, 0.f, 0.f, 0.f}, acc1 = {0.f, 0.f, 0.f, 0.f};
#pragma unroll
    for (int ky = 0; ky < 3; ky++) {
      int slot = (i + ky) % 3;
#pragma unroll
      for (int kx = 0; kx < 3; kx++) {
        f16x8 a = win[slot * 3 + kx];
        acc0 = __builtin_amdgcn_mfma_f32_16x16x32_f16(a, wf[2 * (ky * 3 + kx)], acc0, 0, 0, 0);
        acc1 = __builtin_amdgcn_mfma_f32_16x16x32_f16(a, wf[2 * (ky * 3 + kx) + 1], acc1, 0, 0, 0);
      }
    }
    if (SKIP == 2) {
      const int Ws = 2 * W;
      f16x8 as = *(const f16x8*)(sb + ((size_t)(2 * y) * Ws + 2 * x) * 32 + q * 8);
      acc0 = __builtin_amdgcn_mfma_f32_16x16x32_f16(as, wsf0, acc0, 0, 0, 0);
      acc1 = __builtin_amdgcn_mfma_f32_16x16x32_f16(as, wsf1, acc1, 0, 0, 0);
    }
#pragma unroll
    for (int r = 0; r < 4; r++) {
      size_t px = (size_t)y * W + (tx << 4) + q * 4 + r;
      float v0 = acc0[r] + b0;
      float v1 = acc1[r] + b1;
      if (SKIP == 1) {
        v0 += (float)sb[px * 32 + n];
        v1 += (float)sb[px * 32 + 16 + n];
      }
      ro[px * 32 + n] = (f16)v0;
      ro[px * 32 + 16 + n] = (f16)v1;
      sm0 += v0; sq0 += v0 * v0;
      sm1 += v1; sq1 += v1 * v1;
    }
    if (i + 1 < LEN) rownorm(y0 + i + 2, pf, &win[(i % 3) * 3]);
  }
  if (ostats) {
    sm0 += __shfl_xor(sm0, 16); sm0 += __shfl_xor(sm0, 32);
    sq0 += __shfl_xor(sq0, 16); sq0 += __shfl_xor(sq0, 32);
    sm1 += __shfl_xor(sm1, 16); sm1 += __shfl_xor(sm1, 32);
    sq1 += __shfl_xor(sq1, 16); sq1 += __shfl_xor(sq1, 32);
    if (l < 16) {
      atomicAdd(&ostats[b * 32 + n].x, sm0);
      atomicAdd(&ostats[b * 32 + n].y, sq0);
      atomicAdd(&ostats[b * 32 + 16 + n].x, sm1);
      atomicAdd(&ostats[b * 32 + 16 + n].y, sq1);
    }
  }
}

// ---------------- MFMA 3x3 conv (R7 version): stride-2 and 16x16 ----------
template <int WIN, int STRIDE, int SKIP>
__global__ __launch_bounds__(256) void conv3n(
    const f16* __restrict__ Rin, const float2* __restrict__ SPin, float inv_hw,
    const f16* __restrict__ wp, const float* __restrict__ bias,
    const float* __restrict__ bias2, const f16* __restrict__ skip,
    const f16* __restrict__ wps, f16* __restrict__ Rout,
    float2* __restrict__ ostats) {
  constexpr int WOUT = WIN / STRIDE;
  constexpr int TPR = WOUT / 16;
  constexpr int RPB = (WOUT >= 32) ? 4 : 8;
  constexpr int UNITS = TPR * RPB;
  constexpr int U = UNITS / 4;
  const int t = threadIdx.x, w = t >> 6, l = t & 63;
  const int n = l & 15, q = l >> 4;
  const int b = blockIdx.z;
  const int yb = blockIdx.x * RPB;
  const f16* Rb = Rin + (size_t)b * WIN * WIN * 32;

  f16x8 sc, sh;
#pragma unroll
  for (int j = 0; j < 8; j++) {
    float2 s = SPin[b * 32 + q * 8 + j];
    float mean = s.x * inv_hw;
    float rstd = rsqrtf(s.y * inv_hw - mean * mean + INORM_EPS);
    sc[j] = (f16)rstd;
    sh[j] = (f16)(-mean * rstd);
  }

  f16x8 wf[18];
#pragma unroll
  for (int i = 0; i < 18; i++) wf[i] = *(const f16x8*)(wp + i * 512 + l * 8);
  f16x8 wsf0, wsf1;
  if (SKIP == 2) {
    wsf0 = *(const f16x8*)(wps + l * 8);
    wsf1 = *(const f16x8*)(wps + 512 + l * 8);
  }
  float b0 = bias[n], b1 = bias[16 + n];
  if (SKIP == 2) { b0 += bias2[n]; b1 += bias2[16 + n]; }

  f16* ro = Rout + (size_t)b * WOUT * WOUT * 32;
  const f16* sb = skip ? skip + (size_t)b * (SKIP == 2 ? 4 : 1) * WOUT * WOUT * 32 : nullptr;

  auto load_u = [&](int u, f16x8* a) {
    int ty = u / TPR, tx = u % TPR;
    int y = yb + ty;
#pragma unroll
    for (int kx = 0; kx < 3; kx++) {
      int gx = STRIDE * ((tx << 4) + n) + kx - 1;
      int gxc = min(max(gx, 0), WIN - 1);
#pragma unroll
      for (int ky = 0; ky < 3; ky++) {
        int gy = STRIDE * y + ky - 1;
        int gyc = min(max(gy, 0), WIN - 1);
        a[ky * 3 + kx] = *(const f16x8*)(Rb + ((size_t)gyc * WIN + gxc) * 32 + q * 8);
      }
    }
  };
  auto norm_u = [&](int u, f16x8* a) {
    int ty = u / TPR, tx = u % TPR;
    int y = yb + ty;
#pragma unroll
    for (int kx = 0; kx < 3; kx++) {
      int gx = STRIDE * ((tx << 4) + n) + kx - 1;
      bool okx = (unsigned)gx < (unsigned)WIN;
#pragma unroll
      for (int ky = 0; ky < 3; ky++) {
        int gy = STRIDE * y + ky - 1;
        bool ok = okx && ((unsigned)gy < (unsigned)WIN);
        f16x8 v = a[ky * 3 + kx] * sc + sh;
#pragma unroll
        for (int e = 0; e < 8; e++) v[e] = v[e] > (f16)0 ? v[e] : (f16)0;
        f16x8 z = {};
        a[ky * 3 + kx] = ok ? v : z;
      }
    }
  };

  float sm0 = 0.f, sq0 = 0.f, sm1 = 0.f, sq1 = 0.f;
  f16x8 araw[9], anxt[9];
  load_u(w, araw);
#pragma unroll
  for (int i = 0; i < U; i++) {
    int u = w + 4 * i;
    if (i + 1 < U) load_u(u + 4, anxt);
    norm_u(u, araw);
    int ty = u / TPR, tx = u % TPR;
    int y = yb + ty, x0 = tx << 4;
    f32x4 acc0 = {0.f, 0.f, 0.f, 0.f}, acc1 = {0.f, 0.f, 0.f, 0.f};
#pragma unroll
    for (int p = 0; p < 9; p++) {
      acc0 = __builtin_amdgcn_mfma_f32_16x16x32_f16(araw[p], wf[2 * p], acc0, 0, 0, 0);
      acc1 = __builtin_amdgcn_mfma_f32_16x16x32_f16(araw[p], wf[2 * p + 1], acc1, 0, 0, 0);
    }
    if (SKIP == 2) {
      const int Ws = 2 * WOUT;
      f16x8 as = *(const f16x8*)(sb + ((size_t)(2 * y) * Ws + 2 * (x0 + n)) * 32 + q * 8);
      acc0 = __builtin_amdgcn_mfma_f32_16x16x32_f16(as, wsf0, acc0, 0, 0, 0);
      acc1 = __builtin_amdgcn_mfma_f32_16x16x32_f16(as, wsf1, acc1, 0, 0, 0);
    }
#pragma unroll
    for (int r = 0; r < 4; r++) {
      size_t px = (size_t)y * WOUT + x0 + q * 4 + r;
      float v0 = acc0[r] + b0;
      float v1 = acc1[r] + b1;
      if (SKIP == 1) {
        v0 += (float)sb[px * 32 + n];
        v1 += (float)sb[px * 32 + 16 + n];
      }
      ro[px * 32 + n] = (f16)v0;
      ro[px * 32 + 16 + n] = (f16)v1;
      sm0 += v0; sq0 += v0 * v0;
      sm1 += v1; sq1 += v1 * v1;
    }
#pragma unroll
    for (int p = 0; p < 9; p++) araw[p] = anxt[p];
  }
  if (ostats) {
    sm0 += __shfl_xor(sm0, 16); sm0 += __shfl_xor(sm0, 32);
    sq0 += __shfl_xor(sq0, 16); sq0 += __shfl_xor(sq0, 32);
    sm1 += __shfl_xor(sm1, 16); sm1 += __shfl_xor(sm1, 32);
    sq1 += __shfl_xor(sq1, 16); sq1 += __shfl_xor(sq1, 32);
    if (l < 16) {
      atomicAdd(&ostats[b * 32 + n].x, sm0);
      atomicAdd(&ostats[b * 32 + n].y, sq0);
      atomicAdd(&ostats[b * 32 + 16 + n].x, sm1);
      atomicAdd(&ostats[b * 32 + 16 + n].y, sq1);
    }
  }
}

// ---------------- MFMA 7x7 s2 conv1: 8 rows/block, rolling 7-row window ---
// Wave owns 2 columns; within a column consecutive output rows share 5 of 7
// input rows -> 2 new loads/unit instead of 7.
__global__ __launch_bounds__(256) void conv7(
    const f16* __restrict__ xP, const f16* __restrict__ wp,
    const float* __restrict__ bias, f16* __restrict__ Rout,
    float2* __restrict__ ostats) {
  const int t = threadIdx.x, w = t >> 6, l = t & 63;
  const int n = l & 15, q = l >> 4;
  const int b = blockIdx.z;
  const int yb = blockIdx.x * 8;
  const f16* Xb = xP + (size_t)b * 68644 * 4;
  f16x8 wf[14];
#pragma unroll
  for (int i = 0; i < 14; i++) wf[i] = *(const f16x8*)(wp + i * 512 + l * 8);
  float b0 = bias[n], b1 = bias[16 + n];
  float sm0 = 0.f, sq0 = 0.f, sm1 = 0.f, sq1 = 0.f;
  f16* ro = Rout + (size_t)b * 16384 * 32;

#pragma unroll
  for (int seg = 0; seg < 2; seg++) {
    const int tx = w + seg * 4;
    const int x0 = tx * 16;
    const f16* base = Xb + (size_t)(2 * (x0 + n) + 2 * q) * 4;
    // window: input rows j (absolute 2*yb + j), slot = j % 7
    f16x8 win[7];
#pragma unroll
    for (int j = 0; j < 7; j++)
      win[j] = *(const f16x8*)(base + (size_t)(2 * yb + j) * 1048);
    f16x8 pf0, pf1;
#pragma unroll
    for (int i = 0; i < 8; i++) {
      if (i < 7) {
        pf0 = *(const f16x8*)(base + (size_t)(2 * yb + 2 * i + 7) * 1048);
        pf1 = *(const f16x8*)(base + (size_t)(2 * yb + 2 * i + 8) * 1048);
      }
      int y = yb + i;
      f32x4 acc0 = {0.f, 0.f, 0.f, 0.f}, acc1 = {0.f, 0.f, 0.f, 0.f};
#pragma unroll
      for (int ky = 0; ky < 7; ky++) {
        f16x8 a = win[(2 * i + ky) % 7];
        acc0 = __builtin_amdgcn_mfma_f32_16x16x32_f16(a, wf[2 * ky], acc0, 0, 0, 0);
        acc1 = __builtin_amdgcn_mfma_f32_16x16x32_f16(a, wf[2 * ky + 1], acc1, 0, 0, 0);
      }
#pragma unroll
      for (int r = 0; r < 4; r++) {
        size_t px = (size_t)y * 128 + x0 + q * 4 + r;
        float v0 = acc0[r] + b0;
        float v1 = acc1[r] + b1;
        ro[px * 32 + n] = (f16)v0;
        ro[px * 32 + 16 + n] = (f16)v1;
        sm0 += v0; sq0 += v0 * v0;
        sm1 += v1; sq1 += v1 * v1;
      }
      if (i < 7) {
        win[(2 * i) % 7] = pf0;       // rows 2i, 2i+1 leave; 2i+7, 2i+8 enter
        win[(2 * i + 1) % 7] = pf1;
      }
    }
  }
  sm0 += __shfl_xor(sm0, 16); sm0 += __shfl_xor(sm0, 32);
  sq0 += __shfl_xor(sq0, 16); sq0 += __shfl_xor(sq0, 32);
  sm1 += __shfl_xor(sm1, 16); sm1 += __shfl_xor(sm1, 32);
  sq1 += __shfl_xor(sq1, 16); sq1 += __shfl_xor(sq1, 32);
  if (l < 16) {
    atomicAdd(&ostats[b * 32 + n].x, sm0);
    atomicAdd(&ostats[b * 32 + n].y, sq0);
    atomicAdd(&ostats[b * 32 + 16 + n].x, sm1);
    atomicAdd(&ostats[b * 32 + 16 + n].y, sq1);
  }
}

// ---------------- tail stage 1: gates G[o][b] -----------------------------
__global__ __launch_bounds__(256) void gates_kernel(
    const float* __restrict__ text, const float* __restrict__ attn_w,
    const float* __restrict__ attn_b, float* __restrict__ G) {
  __shared__ float s_text[64 * 257];
  __shared__ float s_w[16 * 256];
  const int t = threadIdx.x, wv = t >> 6, lane = t & 63;
  const int o0 = blockIdx.x * 16;
  for (int d = t; d < 16384; d += 256) {
    int b = d >> 8, k = d & 255;
    s_text[b * 257 + k] = text[d];
  }
  for (int d = t; d < 4096; d += 256) s_w[d] = attn_w[(size_t)o0 * 256 + d];
  __syncthreads();
  float acc[4];
#pragma unroll
  for (int j = 0; j < 4; j++) acc[j] = attn_b[o0 + wv * 4 + j];
  for (int k = 0; k < 256; k++) {
    float tv = s_text[lane * 257 + k];
#pragma unroll
    for (int j = 0; j < 4; j++) acc[j] = fmaf(s_w[(wv * 4 + j) * 256 + k], tv, acc[j]);
  }
#pragma unroll
  for (int j = 0; j < 4; j++) {
    int o = o0 + wv * 4 + j;
    G[o * 64 + lane] = 1.f / (1.f + __expf(-acc[j]));
  }
}

// ---------------- tail stage 2: scores -> softmax -> amapT ----------------
__global__ __launch_bounds__(256) void scores_kernel(
    const f16* __restrict__ feat, const float* __restrict__ G,
    float* __restrict__ amapT) {
  __shared__ float s_feat[256 * 33];
  __shared__ float s_gate[1280];
  __shared__ float s_scores[5 * 32];
  __shared__ float s_probs[5 * 32];
  const int b = blockIdx.x;
  const int t = threadIdx.x;

  for (int i = t; i < 8192; i += 256)
    s_feat[(i >> 5) * 33 + (i & 31)] = (float)feat[(size_t)b * 8192 + i];
  for (int i = t; i < 1280; i += 256) s_gate[i] = G[i * 64 + b];
  __syncthreads();

  if (t < 160) {
    int h = t >> 5, c = t & 31;
    float acc = 0.f;
    for (int ij = 0; ij < 256; ij++) acc += s_gate[h * 256 + ij] * s_feat[ij * 33 + c];
    s_scores[t] = acc;
  }
  __syncthreads();

  if (t < 5) {
    float mx = -1e30f;
    for (int c = 0; c < 32; c++) mx = fmaxf(mx, s_scores[t * 32 + c]);
    float sum = 0.f;
    for (int c = 0; c < 32; c++) {
      float e = __expf(s_scores[t * 32 + c] - mx);
      s_probs[t * 32 + c] = e;
      sum += e;
    }
    float inv = 1.f / sum;
    for (int c = 0; c < 32; c++) s_probs[t * 32 + c] *= inv;
  }
  __syncthreads();

  for (int h = 0; h < 5; h++) {
    float acc = 0.f;
    for (int c = 0; c < 32; c++) acc += s_probs[h * 32 + c] * s_feat[t * 33 + c];
    amapT[(h * 256 + t) * 64 + b] = acc;
  }
}

// ---------------- tail stage 3: final linear ------------------------------
__global__ __launch_bounds__(256) void final_kernel(
    const float* __restrict__ amapT, const float* __restrict__ final_w,
    const float* __restrict__ final_b, float* __restrict__ out) {
  __shared__ float s_w[8 * 1280];
  const int t = threadIdx.x, wv = t >> 6, lane = t & 63;
  const int e0 = blockIdx.x * 8;
  for (int d = t; d < 10240; d += 256) s_w[d] = final_w[(size_t)e0 * 1280 + d];
  __syncthreads();
  float acc0 = final_b[e0 + wv * 2];
  float acc1 = final_b[e0 + wv * 2 + 1];
  for (int k = 0; k < 1280; k++) {
    float av = amapT[k * 64 + lane];
    acc0 = fmaf(s_w[(wv * 2) * 1280 + k], av, acc0);
    acc1 = fmaf(s_w[(wv * 2 + 1) * 1280 + k], av, acc1);
  }
  out[(size_t)lane * 512 + e0 + wv * 2] = acc0;
  out[(size_t)lane * 512 + e0 + wv * 2 + 1] = acc1;
}

// -------------------------------------------------------------------------
extern "C" void kernel_launch(void* const* d_in, const int* in_sizes, int n_in,
                              void* d_out, int out_size, void* d_ws, size_t ws_size,
                              hipStream_t stream) {
  (void)in_sizes; (void)n_in; (void)out_size; (void)ws_size;
  const float* x       = (const float*)d_in[0];
  const float* text    = (const float*)d_in[1];
  const float* conv1_w = (const float*)d_in[2];
  const float* conv1_b = (const float*)d_in[3];
  const float* rbs_w1  = (const float*)d_in[4];
  const float* rbs_b1  = (const float*)d_in[5];
  const float* rbs_w2  = (const float*)d_in[6];
  const float* rbs_b2  = (const float*)d_in[7];
  const float* rbs_ws  = (const float*)d_in[8];
  const float* rbs_bs  = (const float*)d_in[9];
  const float* rb_w1   = (const float*)d_in[10];
  const float* rb_b1   = (const float*)d_in[11];
  const float* rb_w2   = (const float*)d_in[12];
  const float* rb_b2   = (const float*)d_in[13];
  const float* attn_w  = (const float*)d_in[14];
  const float* attn_b  = (const float*)d_in[15];
  const float* final_w = (const float*)d_in[16];
  const float* final_b = (const float*)d_in[17];
  float* out = (float*)d_out;

  char* wsb = (char*)d_ws;
  f16*   xP   = (f16*)(wsb + 0);              // 35,145,728
  f16*   R128 = (f16*)(wsb + 35145728);       // 67,108,864
  f16*   R64a = (f16*)(wsb + 102254592);      // 16,777,216
  f16*   R64b = (f16*)(wsb + 119031808);
  f16*   R64c = (f16*)(wsb + 135809024);
  f16*   R32a = (f16*)(wsb + 152586240);      // 4,194,304
  f16*   R32b = (f16*)(wsb + 156780544);
  f16*   R32c = (f16*)(wsb + 160974848);
  f16*   R16a = (f16*)(wsb + 165169152);      // 1,048,576
  f16*   R16b = (f16*)(wsb + 166217728);
  float2* SP  = (float2*)(wsb + 167266304);   // 10*2048 float2
  float2* SPx = (float2*)(wsb + 167430144);   // 192 float2
  f16*   wp3  = (f16*)(wsb + 167431680);      // 10*9216
  f16*   wp1  = (f16*)(wsb + 167616000);      // 3*1024
  f16*   wp7  = (f16*)(wsb + 167622144);      // 7168
  float* G     = (float*)(wsb + 167636480);   // 1280*64
  float* amapT = (float*)(wsb + 167964160);   // 1280*64
  float2* SP0 = SP + 0 * 2048;
  float2* SP1 = SP + 1 * 2048;
  float2* SP2 = SP + 2 * 2048;
  float2* SP3 = SP + 3 * 2048;
  float2* SP4 = SP + 4 * 2048;
  float2* SP5 = SP + 5 * 2048;
  float2* SP6 = SP + 6 * 2048;
  float2* SP7 = SP + 7 * 2048;
  float2* SP8 = SP + 8 * 2048;
  float2* SP9 = SP + 9 * 2048;

  // prep (merged) + input stats + input pack
  prep<<<480, 256, 0, stream>>>(rbs_w1, rbs_w2, rb_w1, rb_w2, rbs_ws, conv1_w,
                                SP, wp3, wp1, wp7);
  stats_raw<<<192, 256, 0, stream>>>(x, SPx, 65536);
  packx<<<dim3(269, 1, 64), 256, 0, stream>>>(x, SPx, xP);

  // conv1: 7x7 s2, 3->32, 256^2 -> 128^2 (8 rows/block, rolling window)
  conv7<<<dim3(16, 1, 64), 256, 0, stream>>>(xP, wp7, conv1_b, R128, SP0);

  // rbs0: 128^2 -> 64^2
  conv3n<128, 2, 0><<<dim3(16, 1, 64), 256, 0, stream>>>(
      R128, SP0, 1.f / 16384.f, wp3, rbs_b1, nullptr, nullptr, nullptr, R64a, SP1);
  conv3r<64, 2><<<dim3(8, 1, 64), 256, 0, stream>>>(
      R64a, SP1, 1.f / 4096.f, wp3 + 3 * 9216, rbs_b2, rbs_bs, R128, wp1, R64b, SP2);

  // rb0: 64^2 plain resblock (identity = R64b)
  conv3r<64, 0><<<dim3(8, 1, 64), 256, 0, stream>>>(
      R64b, SP2, 1.f / 4096.f, wp3 + 6 * 9216, rb_b1, nullptr, nullptr, nullptr, R64c, SP3);
  conv3r<64, 1><<<dim3(8, 1, 64), 256, 0, stream>>>(
      R64c, SP3, 1.f / 4096.f, wp3 + 8 * 9216, rb_b2, nullptr, R64b, nullptr, R64a, SP4);

  // rbs1: 64^2 -> 32^2 (skip src = R64a)
  conv3n<64, 2, 0><<<dim3(8, 1, 64), 256, 0, stream>>>(
      R64a, SP4, 1.f / 4096.f, wp3 + 1 * 9216, rbs_b1 + 32, nullptr, nullptr, nullptr, R32a, SP5);
  conv3r<32, 2><<<dim3(4, 1, 64), 256, 0, stream>>>(
      R32a, SP5, 1.f / 1024.f, wp3 + 4 * 9216, rbs_b2 + 32, rbs_bs + 32, R64a, wp1 + 1024, R32b, SP6);

  // rb1: 32^2 plain resblock (identity = R32b)
  conv3r<32, 0><<<dim3(4, 1, 64), 256, 0, stream>>>(
      R32b, SP6, 1.f / 1024.f, wp3 + 7 * 9216, rb_b1 + 32, nullptr, nullptr, nullptr, R32c, SP7);
  conv3r<32, 1><<<dim3(4, 1, 64), 256, 0, stream>>>(
      R32c, SP7, 1.f / 1024.f, wp3 + 9 * 9216, rb_b2 + 32, nullptr, R32b, nullptr, R32a, SP8);

  // rbs2: 32^2 -> 16^2 (skip src = R32a)
  conv3n<32, 2, 0><<<dim3(2, 1, 64), 256, 0, stream>>>(
      R32a, SP8, 1.f / 1024.f, wp3 + 2 * 9216, rbs_b1 + 64, nullptr, nullptr, nullptr, R16a, SP9);
  conv3n<16, 1, 2><<<dim3(2, 1, 64), 256, 0, stream>>>(
      R16a, SP9, 1.f / 256.f, wp3 + 5 * 9216, rbs_b2 + 64, rbs_bs + 64, R32a, wp1 + 2048, R16b, nullptr);

  // attention tail
  gates_kernel<<<80, 256, 0, stream>>>(text, attn_w, attn_b, G);
  scores_kernel<<<64, 256, 0, stream>>>(R16b, G, amapT);
  final_kernel<<<64, 256, 0, stream>>>(amapT, final_w, final_b, out);
}

// Round 9
// 331.244 us; speedup vs baseline: 2.2176x; 1.1385x over previous
//
#include <hip/hip_runtime.h>
#include <cstdint>
#include <cstddef>

#define INORM_EPS 1e-5f

typedef _Float16 f16;
typedef f16 f16x8 __attribute__((ext_vector_type(8)));
typedef f16 f16x4 __attribute__((ext_vector_type(4)));
typedef float f32x4 __attribute__((ext_vector_type(4)));

// ---------------- one merged prep kernel ----------------------------------
// zero range covers SP (20480) + SPx (192) which are contiguous in ws.
__global__ __launch_bounds__(256) void prep(
    const float* __restrict__ rbs_w1, const float* __restrict__ rbs_w2,
    const float* __restrict__ rb_w1, const float* __restrict__ rb_w2,
    const float* __restrict__ rbs_ws, const float* __restrict__ conv1_w,
    float2* __restrict__ SP, f16* __restrict__ wp3, f16* __restrict__ wp1,
    f16* __restrict__ wp7) {
  int i = blockIdx.x * 256 + threadIdx.x;
  if (i < 20672) { SP[i] = make_float2(0.f, 0.f); return; }
  i -= 20672;
  if (i < 92160) {  // [mat][9 taps][2 halves][64 lanes][8] ; B-frag layout
    int mat = i / 9216, r = i % 9216;
    int p = r >> 10, f = (r >> 9) & 1, l = (r >> 3) & 63, j = r & 7;
    int co = f * 16 + (l & 15), ci = (l >> 4) * 8 + j;
    const float* src; int m;
    if (mat < 3) { src = rbs_w1; m = mat; }
    else if (mat < 6) { src = rbs_w2; m = mat - 3; }
    else if (mat < 8) { src = rb_w1; m = mat - 6; }
    else { src = rb_w2; m = mat - 8; }
    wp3[i] = (f16)src[m * 9216 + co * 288 + ci * 9 + p];
    return;
  }
  i -= 92160;
  if (i < 3072) {
    int mat = i / 1024, r = i % 1024;
    int f = r >> 9, l = (r >> 3) & 63, j = r & 7;
    wp1[i] = (f16)rbs_ws[mat * 1024 + (f * 16 + (l & 15)) * 32 + (l >> 4) * 8 + j];
    return;
  }
  i -= 3072;
  if (i >= 7168) return;
  int ky = i >> 10, f = (i >> 9) & 1, l = (i >> 3) & 63, j = i & 7;
  int k = (l >> 4) * 8 + j, kx = k >> 2, ci = k & 3;
  float v = 0.f;
  if (kx < 7 && ci < 3) v = conv1_w[(f * 16 + (l & 15)) * 147 + ci * 49 + ky * 7 + kx];
  wp7[i] = (f16)v;
}

// ---------------- raw (sum, sumsq) stats, 8 chunks per map ----------------
__global__ __launch_bounds__(256) void stats_raw(const float* __restrict__ in,
                                                 float2* __restrict__ st, int HW) {
  const int map = blockIdx.x >> 3, chunk = blockIdx.x & 7;
  const int n4 = HW >> 5;  // chunk elems / 4
  const float4* p = (const float4*)(in + (size_t)map * HW + (size_t)chunk * (HW >> 3));
  float s = 0.f, ss = 0.f;
  for (int i = threadIdx.x; i < n4; i += 256) {
    float4 v = p[i];
    s += v.x + v.y + v.z + v.w;
    ss += v.x * v.x + v.y * v.y + v.z * v.z + v.w * v.w;
  }
  __shared__ float r0[256], r1[256];
  r0[threadIdx.x] = s;
  r1[threadIdx.x] = ss;
  __syncthreads();
  for (int off = 128; off > 0; off >>= 1) {
    if ((int)threadIdx.x < off) {
      r0[threadIdx.x] += r0[threadIdx.x + off];
      r1[threadIdx.x] += r1[threadIdx.x + off];
    }
    __syncthreads();
  }
  if (threadIdx.x == 0) {
    atomicAdd(&st[map].x, r0[0]);
    atomicAdd(&st[map].y, r1[0]);
  }
}

// ---- pack x: fp32 NCHW -> normed padded f16 [64][262][262][4] ------------
__global__ __launch_bounds__(256) void packx(const float* __restrict__ x,
                                             const float2* __restrict__ SPx,
                                             f16* __restrict__ xP) {
  int u = blockIdx.x * 256 + threadIdx.x;
  if (u >= 262 * 262) return;
  int b = blockIdx.z;
  int r = u / 262, c = u % 262;
  f16x4 out;
  out[0] = (f16)0; out[1] = (f16)0; out[2] = (f16)0; out[3] = (f16)0;
  if (r >= 3 && r < 259 && c >= 3 && c < 259) {
    int ir = r - 3, ic = c - 3;
#pragma unroll
    for (int ci = 0; ci < 3; ci++) {
      float2 s = SPx[b * 3 + ci];
      float mean = s.x * (1.f / 65536.f);
      float rstd = rsqrtf(s.y * (1.f / 65536.f) - mean * mean + INORM_EPS);
      out[ci] = (f16)((x[((size_t)b * 3 + ci) * 65536 + ir * 256 + ic] - mean) * rstd);
    }
  }
  *(f16x4*)(xP + ((size_t)b * 68644 + u) * 4) = out;
}

// ---------------- MFMA 3x3 stride-1 conv, rolling row window --------------
template <int W, int SKIP>
__global__ __launch_bounds__(256) void conv3r(
    const f16* __restrict__ Rin, const float2* __restrict__ SPin, float inv_hw,
    const f16* __restrict__ wp, const float* __restrict__ bias,
    const float* __restrict__ bias2, const f16* __restrict__ skip,
    const f16* __restrict__ wps, f16* __restrict__ Rout,
    float2* __restrict__ ostats) {
  constexpr int TPR = W / 16;
  constexpr int RPB = 8;
  constexpr int LEN = (RPB * TPR) / 4;
  const int t = threadIdx.x, w = t >> 6, l = t & 63;
  const int n = l & 15, q = l >> 4;
  const int b = blockIdx.z;
  const int tx = w % TPR;
  const int y0 = blockIdx.x * RPB + (w / TPR) * LEN;
  const int x = (tx << 4) + n;
  const f16* Rb = Rin + (size_t)b * W * W * 32;

  f16x8 sc, sh;
#pragma unroll
  for (int j = 0; j < 8; j++) {
    float2 s = SPin[b * 32 + q * 8 + j];
    float mean = s.x * inv_hw;
    float rstd = rsqrtf(s.y * inv_hw - mean * mean + INORM_EPS);
    sc[j] = (f16)rstd;
    sh[j] = (f16)(-mean * rstd);
  }

  f16x8 wf[18];
#pragma unroll
  for (int i = 0; i < 18; i++) wf[i] = *(const f16x8*)(wp + i * 512 + l * 8);
  f16x8 wsf0, wsf1;
  if (SKIP == 2) {
    wsf0 = *(const f16x8*)(wps + l * 8);
    wsf1 = *(const f16x8*)(wps + 512 + l * 8);
  }
  float b0 = bias[n], b1 = bias[16 + n];
  if (SKIP == 2) { b0 += bias2[n]; b1 += bias2[16 + n]; }

  f16* ro = Rout + (size_t)b * W * W * 32;
  const f16* sb = skip ? skip + (size_t)b * (SKIP == 2 ? 4 : 1) * W * W * 32 : nullptr;

  bool okc[3];
#pragma unroll
  for (int kx = 0; kx < 3; kx++) okc[kx] = (unsigned)(x + kx - 1) < (unsigned)W;

  auto rowload = [&](int gy, f16x8* dst) {
    int gyc = min(max(gy, 0), W - 1);
#pragma unroll
    for (int kx = 0; kx < 3; kx++) {
      int gxc = min(max(x + kx - 1, 0), W - 1);
      dst[kx] = *(const f16x8*)(Rb + ((size_t)gyc * W + gxc) * 32 + q * 8);
    }
  };
  auto rownorm = [&](int gy, const f16x8* src, f16x8* dst) {
    bool okr = (unsigned)gy < (unsigned)W;
#pragma unroll
    for (int kx = 0; kx < 3; kx++) {
      f16x8 v = src[kx] * sc + sh;
#pragma unroll
      for (int e = 0; e < 8; e++) v[e] = v[e] > (f16)0 ? v[e] : (f16)0;
      f16x8 z = {};
      dst[kx] = (okr && okc[kx]) ? v : z;
    }
  };

  float sm0 = 0.f, sq0 = 0.f, sm1 = 0.f, sq1 = 0.f;
  f16x8 win[9];
  f16x8 tmp[3], pf[3];
#pragma unroll
  for (int jj = 0; jj < 3; jj++) {
    rowload(y0 + jj - 1, tmp);
    rownorm(y0 + jj - 1, tmp, &win[jj * 3]);
  }

#pragma unroll
  for (int i = 0; i < LEN; i++) {
    int y = y0 + i;
    if (i + 1 < LEN) rowload(y0 + i + 2, pf);
    f32x4 acc0 = {0.f, 0.f, 0.f, 0.f}, acc1 = {0.f, 0.f, 0.f, 0.f};
#pragma unroll
    for (int ky = 0; ky < 3; ky++) {
      int slot = (i + ky) % 3;
#pragma unroll
      for (int kx = 0; kx < 3; kx++) {
        f16x8 a = win[slot * 3 + kx];
        acc0 = __builtin_amdgcn_mfma_f32_16x16x32_f16(a, wf[2 * (ky * 3 + kx)], acc0, 0, 0, 0);
        acc1 = __builtin_amdgcn_mfma_f32_16x16x32_f16(a, wf[2 * (ky * 3 + kx) + 1], acc1, 0, 0, 0);
      }
    }
    if (SKIP == 2) {
      const int Ws = 2 * W;
      f16x8 as = *(const f16x8*)(sb + ((size_t)(2 * y) * Ws + 2 * x) * 32 + q * 8);
      acc0 = __builtin_amdgcn_mfma_f32_16x16x32_f16(as, wsf0, acc0, 0, 0, 0);
      acc1 = __builtin_amdgcn_mfma_f32_16x16x32_f16(as, wsf1, acc1, 0, 0, 0);
    }
#pragma unroll
    for (int r = 0; r < 4; r++) {
      size_t px = (size_t)y * W + (tx << 4) + q * 4 + r;
      float v0 = acc0[r] + b0;
      float v1 = acc1[r] + b1;
      if (SKIP == 1) {
        v0 += (float)sb[px * 32 + n];
        v1 += (float)sb[px * 32 + 16 + n];
      }
      ro[px * 32 + n] = (f16)v0;
      ro[px * 32 + 16 + n] = (f16)v1;
      sm0 += v0; sq0 += v0 * v0;
      sm1 += v1; sq1 += v1 * v1;
    }
    if (i + 1 < LEN) rownorm(y0 + i + 2, pf, &win[(i % 3) * 3]);
  }
  if (ostats) {
    sm0 += __shfl_xor(sm0, 16); sm0 += __shfl_xor(sm0, 32);
    sq0 += __shfl_xor(sq0, 16); sq0 += __shfl_xor(sq0, 32);
    sm1 += __shfl_xor(sm1, 16); sm1 += __shfl_xor(sm1, 32);
    sq1 += __shfl_xor(sq1, 16); sq1 += __shfl_xor(sq1, 32);
    if (l < 16) {
      atomicAdd(&ostats[b * 32 + n].x, sm0);
      atomicAdd(&ostats[b * 32 + n].y, sq0);
      atomicAdd(&ostats[b * 32 + 16 + n].x, sm1);
      atomicAdd(&ostats[b * 32 + 16 + n].y, sq1);
    }
  }
}

// ---------------- MFMA 3x3 conv (pipelined units): stride-2 and 16x16 -----
template <int WIN, int STRIDE, int SKIP>
__global__ __launch_bounds__(256) void conv3n(
    const f16* __restrict__ Rin, const float2* __restrict__ SPin, float inv_hw,
    const f16* __restrict__ wp, const float* __restrict__ bias,
    const float* __restrict__ bias2, const f16* __restrict__ skip,
    const f16* __restrict__ wps, f16* __restrict__ Rout,
    float2* __restrict__ ostats) {
  constexpr int WOUT = WIN / STRIDE;
  constexpr int TPR = WOUT / 16;
  constexpr int RPB = (WOUT >= 32) ? 4 : 8;
  constexpr int UNITS = TPR * RPB;
  constexpr int U = UNITS / 4;
  const int t = threadIdx.x, w = t >> 6, l = t & 63;
  const int n = l & 15, q = l >> 4;
  const int b = blockIdx.z;
  const int yb = blockIdx.x * RPB;
  const f16* Rb = Rin + (size_t)b * WIN * WIN * 32;

  f16x8 sc, sh;
#pragma unroll
  for (int j = 0; j < 8; j++) {
    float2 s = SPin[b * 32 + q * 8 + j];
    float mean = s.x * inv_hw;
    float rstd = rsqrtf(s.y * inv_hw - mean * mean + INORM_EPS);
    sc[j] = (f16)rstd;
    sh[j] = (f16)(-mean * rstd);
  }

  f16x8 wf[18];
#pragma unroll
  for (int i = 0; i < 18; i++) wf[i] = *(const f16x8*)(wp + i * 512 + l * 8);
  f16x8 wsf0, wsf1;
  if (SKIP == 2) {
    wsf0 = *(const f16x8*)(wps + l * 8);
    wsf1 = *(const f16x8*)(wps + 512 + l * 8);
  }
  float b0 = bias[n], b1 = bias[16 + n];
  if (SKIP == 2) { b0 += bias2[n]; b1 += bias2[16 + n]; }

  f16* ro = Rout + (size_t)b * WOUT * WOUT * 32;
  const f16* sb = skip ? skip + (size_t)b * (SKIP == 2 ? 4 : 1) * WOUT * WOUT * 32 : nullptr;

  auto load_u = [&](int u, f16x8* a) {
    int ty = u / TPR, tx = u % TPR;
    int y = yb + ty;
#pragma unroll
    for (int kx = 0; kx < 3; kx++) {
      int gx = STRIDE * ((tx << 4) + n) + kx - 1;
      int gxc = min(max(gx, 0), WIN - 1);
#pragma unroll
      for (int ky = 0; ky < 3; ky++) {
        int gy = STRIDE * y + ky - 1;
        int gyc = min(max(gy, 0), WIN - 1);
        a[ky * 3 + kx] = *(const f16x8*)(Rb + ((size_t)gyc * WIN + gxc) * 32 + q * 8);
      }
    }
  };
  auto norm_u = [&](int u, f16x8* a) {
    int ty = u / TPR, tx = u % TPR;
    int y = yb + ty;
#pragma unroll
    for (int kx = 0; kx < 3; kx++) {
      int gx = STRIDE * ((tx << 4) + n) + kx - 1;
      bool okx = (unsigned)gx < (unsigned)WIN;
#pragma unroll
      for (int ky = 0; ky < 3; ky++) {
        int gy = STRIDE * y + ky - 1;
        bool ok = okx && ((unsigned)gy < (unsigned)WIN);
        f16x8 v = a[ky * 3 + kx] * sc + sh;
#pragma unroll
        for (int e = 0; e < 8; e++) v[e] = v[e] > (f16)0 ? v[e] : (f16)0;
        f16x8 z = {};
        a[ky * 3 + kx] = ok ? v : z;
      }
    }
  };

  float sm0 = 0.f, sq0 = 0.f, sm1 = 0.f, sq1 = 0.f;
  f16x8 araw[9], anxt[9];
  load_u(w, araw);
#pragma unroll
  for (int i = 0; i < U; i++) {
    int u = w + 4 * i;
    if (i + 1 < U) load_u(u + 4, anxt);
    norm_u(u, araw);
    int ty = u / TPR, tx = u % TPR;
    int y = yb + ty, x0 = tx << 4;
    f32x4 acc0 = {0.f, 0.f, 0.f, 0.f}, acc1 = {0.f, 0.f, 0.f, 0.f};
#pragma unroll
    for (int p = 0; p < 9; p++) {
      acc0 = __builtin_amdgcn_mfma_f32_16x16x32_f16(araw[p], wf[2 * p], acc0, 0, 0, 0);
      acc1 = __builtin_amdgcn_mfma_f32_16x16x32_f16(araw[p], wf[2 * p + 1], acc1, 0, 0, 0);
    }
    if (SKIP == 2) {
      const int Ws = 2 * WOUT;
      f16x8 as = *(const f16x8*)(sb + ((size_t)(2 * y) * Ws + 2 * (x0 + n)) * 32 + q * 8);
      acc0 = __builtin_amdgcn_mfma_f32_16x16x32_f16(as, wsf0, acc0, 0, 0, 0);
      acc1 = __builtin_amdgcn_mfma_f32_16x16x32_f16(as, wsf1, acc1, 0, 0, 0);
    }
#pragma unroll
    for (int r = 0; r < 4; r++) {
      size_t px = (size_t)y * WOUT + x0 + q * 4 + r;
      float v0 = acc0[r] + b0;
      float v1 = acc1[r] + b1;
      if (SKIP == 1) {
        v0 += (float)sb[px * 32 + n];
        v1 += (float)sb[px * 32 + 16 + n];
      }
      ro[px * 32 + n] = (f16)v0;
      ro[px * 32 + 16 + n] = (f16)v1;
      sm0 += v0; sq0 += v0 * v0;
      sm1 += v1; sq1 += v1 * v1;
    }
#pragma unroll
    for (int p = 0; p < 9; p++) araw[p] = anxt[p];
  }
  if (ostats) {
    sm0 += __shfl_xor(sm0, 16); sm0 += __shfl_xor(sm0, 32);
    sq0 += __shfl_xor(sq0, 16); sq0 += __shfl_xor(sq0, 32);
    sm1 += __shfl_xor(sm1, 16); sm1 += __shfl_xor(sm1, 32);
    sq1 += __shfl_xor(sq1, 16); sq1 += __shfl_xor(sq1, 32);
    if (l < 16) {
      atomicAdd(&ostats[b * 32 + n].x, sm0);
      atomicAdd(&ostats[b * 32 + n].y, sq0);
      atomicAdd(&ostats[b * 32 + 16 + n].x, sm1);
      atomicAdd(&ostats[b * 32 + 16 + n].y, sq1);
    }
  }
}

// ---------------- MFMA 7x7 s2 conv1: 8 rows/block, rolling 7-row window ---
__global__ __launch_bounds__(256) void conv7(
    const f16* __restrict__ xP, const f16* __restrict__ wp,
    const float* __restrict__ bias, f16* __restrict__ Rout,
    float2* __restrict__ ostats) {
  const int t = threadIdx.x, w = t >> 6, l = t & 63;
  const int n = l & 15, q = l >> 4;
  const int b = blockIdx.z;
  const int yb = blockIdx.x * 8;
  const f16* Xb = xP + (size_t)b * 68644 * 4;
  f16x8 wf[14];
#pragma unroll
  for (int i = 0; i < 14; i++) wf[i] = *(const f16x8*)(wp + i * 512 + l * 8);
  float b0 = bias[n], b1 = bias[16 + n];
  float sm0 = 0.f, sq0 = 0.f, sm1 = 0.f, sq1 = 0.f;
  f16* ro = Rout + (size_t)b * 16384 * 32;

#pragma unroll
  for (int seg = 0; seg < 2; seg++) {
    const int tx = w + seg * 4;
    const int x0 = tx * 16;
    const f16* base = Xb + (size_t)(2 * (x0 + n) + 2 * q) * 4;
    f16x8 win[7];
#pragma unroll
    for (int j = 0; j < 7; j++)
      win[j] = *(const f16x8*)(base + (size_t)(2 * yb + j) * 1048);
    f16x8 pf0, pf1;
#pragma unroll
    for (int i = 0; i < 8; i++) {
      if (i < 7) {
        pf0 = *(const f16x8*)(base + (size_t)(2 * yb + 2 * i + 7) * 1048);
        pf1 = *(const f16x8*)(base + (size_t)(2 * yb + 2 * i + 8) * 1048);
      }
      int y = yb + i;
      f32x4 acc0 = {0.f, 0.f, 0.f, 0.f}, acc1 = {0.f, 0.f, 0.f, 0.f};
#pragma unroll
      for (int ky = 0; ky < 7; ky++) {
        f16x8 a = win[(2 * i + ky) % 7];
        acc0 = __builtin_amdgcn_mfma_f32_16x16x32_f16(a, wf[2 * ky], acc0, 0, 0, 0);
        acc1 = __builtin_amdgcn_mfma_f32_16x16x32_f16(a, wf[2 * ky + 1], acc1, 0, 0, 0);
      }
#pragma unroll
      for (int r = 0; r < 4; r++) {
        size_t px = (size_t)y * 128 + x0 + q * 4 + r;
        float v0 = acc0[r] + b0;
        float v1 = acc1[r] + b1;
        ro[px * 32 + n] = (f16)v0;
        ro[px * 32 + 16 + n] = (f16)v1;
        sm0 += v0; sq0 += v0 * v0;
        sm1 += v1; sq1 += v1 * v1;
      }
      if (i < 7) {
        win[(2 * i) % 7] = pf0;
        win[(2 * i + 1) % 7] = pf1;
      }
    }
  }
  sm0 += __shfl_xor(sm0, 16); sm0 += __shfl_xor(sm0, 32);
  sq0 += __shfl_xor(sq0, 16); sq0 += __shfl_xor(sq0, 32);
  sm1 += __shfl_xor(sm1, 16); sm1 += __shfl_xor(sm1, 32);
  sq1 += __shfl_xor(sq1, 16); sq1 += __shfl_xor(sq1, 32);
  if (l < 16) {
    atomicAdd(&ostats[b * 32 + n].x, sm0);
    atomicAdd(&ostats[b * 32 + n].y, sq0);
    atomicAdd(&ostats[b * 32 + 16 + n].x, sm1);
    atomicAdd(&ostats[b * 32 + 16 + n].y, sq1);
  }
}

// ---------------- tail stage 1: gates G[o][b] -----------------------------
__global__ __launch_bounds__(256) void gates_kernel(
    const float* __restrict__ text, const float* __restrict__ attn_w,
    const float* __restrict__ attn_b, float* __restrict__ G) {
  __shared__ float s_text[64 * 257];
  __shared__ float s_w[16 * 256];
  const int t = threadIdx.x, wv = t >> 6, lane = t & 63;
  const int o0 = blockIdx.x * 16;
  for (int d = t; d < 16384; d += 256) {
    int b = d >> 8, k = d & 255;
    s_text[b * 257 + k] = text[d];
  }
  for (int d = t; d < 4096; d += 256) s_w[d] = attn_w[(size_t)o0 * 256 + d];
  __syncthreads();
  float acc[4];
#pragma unroll
  for (int j = 0; j < 4; j++) acc[j] = attn_b[o0 + wv * 4 + j];
  for (int k = 0; k < 256; k++) {
    float tv = s_text[lane * 257 + k];
#pragma unroll
    for (int j = 0; j < 4; j++) acc[j] = fmaf(s_w[(wv * 4 + j) * 256 + k], tv, acc[j]);
  }
#pragma unroll
  for (int j = 0; j < 4; j++) {
    int o = o0 + wv * 4 + j;
    G[o * 64 + lane] = 1.f / (1.f + __expf(-acc[j]));
  }
}

// ---------------- tail stage 2: scores -> softmax -> amapT ----------------
__global__ __launch_bounds__(256) void scores_kernel(
    const f16* __restrict__ feat, const float* __restrict__ G,
    float* __restrict__ amapT) {
  __shared__ float s_feat[256 * 33];
  __shared__ float s_gate[1280];
  __shared__ float s_scores[5 * 32];
  __shared__ float s_probs[5 * 32];
  const int b = blockIdx.x;
  const int t = threadIdx.x;

  for (int i = t; i < 8192; i += 256)
    s_feat[(i >> 5) * 33 + (i & 31)] = (float)feat[(size_t)b * 8192 + i];
  for (int i = t; i < 1280; i += 256) s_gate[i] = G[i * 64 + b];
  __syncthreads();

  if (t < 160) {
    int h = t >> 5, c = t & 31;
    float acc = 0.f;
    for (int ij = 0; ij < 256; ij++) acc += s_gate[h * 256 + ij] * s_feat[ij * 33 + c];
    s_scores[t] = acc;
  }
  __syncthreads();

  if (t < 5) {
    float mx = -1e30f;
    for (int c = 0; c < 32; c++) mx = fmaxf(mx, s_scores[t * 32 + c]);
    float sum = 0.f;
    for (int c = 0; c < 32; c++) {
      float e = __expf(s_scores[t * 32 + c] - mx);
      s_probs[t * 32 + c] = e;
      sum += e;
    }
    float inv = 1.f / sum;
    for (int c = 0; c < 32; c++) s_probs[t * 32 + c] *= inv;
  }
  __syncthreads();

  for (int h = 0; h < 5; h++) {
    float acc = 0.f;
    for (int c = 0; c < 32; c++) acc += s_probs[h * 32 + c] * s_feat[t * 33 + c];
    amapT[(h * 256 + t) * 64 + b] = acc;
  }
}

// ---------------- tail stage 3: final linear, k split across waves --------
// grid 128: block = 4 e's; wave wv handles k in [wv*320,(wv+1)*320);
// 4-way ILP per amapT load; LDS cross-wave reduction.
__global__ __launch_bounds__(256) void final_kernel(
    const float* __restrict__ amapT, const float* __restrict__ final_w,
    const float* __restrict__ final_b, float* __restrict__ out) {
  __shared__ float s_w[4 * 1280];
  __shared__ float s_red[4][4][64];
  const int t = threadIdx.x, wv = t >> 6, lane = t & 63;
  const int e0 = blockIdx.x * 4;
  for (int d = t; d < 5120; d += 256) s_w[d] = final_w[(size_t)e0 * 1280 + d];
  __syncthreads();
  const int k0 = wv * 320;
  float acc[4] = {0.f, 0.f, 0.f, 0.f};
  for (int k = k0; k < k0 + 320; k++) {
    float av = amapT[k * 64 + lane];
#pragma unroll
    for (int e = 0; e < 4; e++) acc[e] = fmaf(s_w[e * 1280 + k], av, acc[e]);
  }
#pragma unroll
  for (int e = 0; e < 4; e++) s_red[wv][e][lane] = acc[e];
  __syncthreads();
  if (wv == 0) {
#pragma unroll
    for (int e = 0; e < 4; e++) {
      float v = s_red[0][e][lane] + s_red[1][e][lane] + s_red[2][e][lane] +
                s_red[3][e][lane] + final_b[e0 + e];
      out[(size_t)lane * 512 + e0 + e] = v;
    }
  }
}

// -------------------------------------------------------------------------
extern "C" void kernel_launch(void* const* d_in, const int* in_sizes, int n_in,
                              void* d_out, int out_size, void* d_ws, size_t ws_size,
                              hipStream_t stream) {
  (void)in_sizes; (void)n_in; (void)out_size; (void)ws_size;
  const float* x       = (const float*)d_in[0];
  const float* text    = (const float*)d_in[1];
  const float* conv1_w = (const float*)d_in[2];
  const float* conv1_b = (const float*)d_in[3];
  const float* rbs_w1  = (const float*)d_in[4];
  const float* rbs_b1  = (const float*)d_in[5];
  const float* rbs_w2  = (const float*)d_in[6];
  const float* rbs_b2  = (const float*)d_in[7];
  const float* rbs_ws  = (const float*)d_in[8];
  const float* rbs_bs  = (const float*)d_in[9];
  const float* rb_w1   = (const float*)d_in[10];
  const float* rb_b1   = (const float*)d_in[11];
  const float* rb_w2   = (const float*)d_in[12];
  const float* rb_b2   = (const float*)d_in[13];
  const float* attn_w  = (const float*)d_in[14];
  const float* attn_b  = (const float*)d_in[15];
  const float* final_w = (const float*)d_in[16];
  const float* final_b = (const float*)d_in[17];
  float* out = (float*)d_out;

  char* wsb = (char*)d_ws;
  f16*   xP   = (f16*)(wsb + 0);              // 35,145,728
  f16*   R128 = (f16*)(wsb + 35145728);       // 67,108,864
  f16*   R64a = (f16*)(wsb + 102254592);      // 16,777,216
  f16*   R64b = (f16*)(wsb + 119031808);
  f16*   R64c = (f16*)(wsb + 135809024);
  f16*   R32a = (f16*)(wsb + 152586240);      // 4,194,304
  f16*   R32b = (f16*)(wsb + 156780544);
  f16*   R32c = (f16*)(wsb + 160974848);
  f16*   R16a = (f16*)(wsb + 165169152);      // 1,048,576
  f16*   R16b = (f16*)(wsb + 166217728);
  float2* SP  = (float2*)(wsb + 167266304);   // 10*2048 float2 (+ SPx right after)
  float2* SPx = (float2*)(wsb + 167430144);   // 192 float2
  f16*   wp3  = (f16*)(wsb + 167431680);      // 10*9216
  f16*   wp1  = (f16*)(wsb + 167616000);      // 3*1024
  f16*   wp7  = (f16*)(wsb + 167622144);      // 7168
  float* G     = (float*)(wsb + 167636480);   // 1280*64
  float* amapT = (float*)(wsb + 167964160);   // 1280*64
  float2* SP0 = SP + 0 * 2048;
  float2* SP1 = SP + 1 * 2048;
  float2* SP2 = SP + 2 * 2048;
  float2* SP3 = SP + 3 * 2048;
  float2* SP4 = SP + 4 * 2048;
  float2* SP5 = SP + 5 * 2048;
  float2* SP6 = SP + 6 * 2048;
  float2* SP7 = SP + 7 * 2048;
  float2* SP8 = SP + 8 * 2048;
  float2* SP9 = SP + 9 * 2048;

  // prep (zeroes SP+SPx, packs weights) + input stats (atomic) + input pack
  prep<<<481, 256, 0, stream>>>(rbs_w1, rbs_w2, rb_w1, rb_w2, rbs_ws, conv1_w,
                                SP, wp3, wp1, wp7);
  stats_raw<<<1536, 256, 0, stream>>>(x, SPx, 65536);
  packx<<<dim3(269, 1, 64), 256, 0, stream>>>(x, SPx, xP);

  // conv1: 7x7 s2, 3->32, 256^2 -> 128^2 (8 rows/block, rolling window)
  conv7<<<dim3(16, 1, 64), 256, 0, stream>>>(xP, wp7, conv1_b, R128, SP0);

  // rbs0: 128^2 -> 64^2
  conv3n<128, 2, 0><<<dim3(16, 1, 64), 256, 0, stream>>>(
      R128, SP0, 1.f / 16384.f, wp3, rbs_b1, nullptr, nullptr, nullptr, R64a, SP1);
  conv3r<64, 2><<<dim3(8, 1, 64), 256, 0, stream>>>(
      R64a, SP1, 1.f / 4096.f, wp3 + 3 * 9216, rbs_b2, rbs_bs, R128, wp1, R64b, SP2);

  // rb0: 64^2 plain resblock (identity = R64b)
  conv3r<64, 0><<<dim3(8, 1, 64), 256, 0, stream>>>(
      R64b, SP2, 1.f / 4096.f, wp3 + 6 * 9216, rb_b1, nullptr, nullptr, nullptr, R64c, SP3);
  conv3r<64, 1><<<dim3(8, 1, 64), 256, 0, stream>>>(
      R64c, SP3, 1.f / 4096.f, wp3 + 8 * 9216, rb_b2, nullptr, R64b, nullptr, R64a, SP4);

  // rbs1: 64^2 -> 32^2 (skip src = R64a)
  conv3n<64, 2, 0><<<dim3(8, 1, 64), 256, 0, stream>>>(
      R64a, SP4, 1.f / 4096.f, wp3 + 1 * 9216, rbs_b1 + 32, nullptr, nullptr, nullptr, R32a, SP5);
  conv3r<32, 2><<<dim3(4, 1, 64), 256, 0, stream>>>(
      R32a, SP5, 1.f / 1024.f, wp3 + 4 * 9216, rbs_b2 + 32, rbs_bs + 32, R64a, wp1 + 1024, R32b, SP6);

  // rb1: 32^2 plain resblock (identity = R32b)
  conv3r<32, 0><<<dim3(4, 1, 64), 256, 0, stream>>>(
      R32b, SP6, 1.f / 1024.f, wp3 + 7 * 9216, rb_b1 + 32, nullptr, nullptr, nullptr, R32c, SP7);
  conv3r<32, 1><<<dim3(4, 1, 64), 256, 0, stream>>>(
      R32c, SP7, 1.f / 1024.f, wp3 + 9 * 9216, rb_b2 + 32, nullptr, R32b, nullptr, R32a, SP8);

  // rbs2: 32^2 -> 16^2 (skip src = R32a)
  conv3n<32, 2, 0><<<dim3(2, 1, 64), 256, 0, stream>>>(
      R32a, SP8, 1.f / 1024.f, wp3 + 2 * 9216, rbs_b1 + 64, nullptr, nullptr, nullptr, R16a, SP9);
  conv3n<16, 1, 2><<<dim3(2, 1, 64), 256, 0, stream>>>(
      R16a, SP9, 1.f / 256.f, wp3 + 5 * 9216, rbs_b2 + 64, rbs_bs + 64, R32a, wp1 + 2048, R16b, nullptr);

  // attention tail
  gates_kernel<<<80, 256, 0, stream>>>(text, attn_w, attn_b, G);
  scores_kernel<<<64, 256, 0, stream>>>(R16b, G, amapT);
  final_kernel<<<128, 256, 0, stream>>>(amapT, final_w, final_b, out);
}